// Round 11
// baseline (2064.548 us; speedup 1.0000x reference)
//
#include <hip/hip_runtime.h>

#define Tn 1024
#define Dn 1024
#define Ln 12
#define F4n 4096
#define Vn 50277
#define TDn (Tn*Dn)
#define MEG 1048576
#define SEG 16
#define NSEG 64

typedef __attribute__((ext_vector_type(4))) float f4;
typedef __attribute__((ext_vector_type(16))) float f32x16;
typedef __attribute__((ext_vector_type(8))) short short8;
typedef unsigned short u16;
typedef unsigned int u32;
typedef __attribute__((ext_vector_type(4))) u16 us4;

#define ASG __attribute__((address_space(1)))
#define ASL __attribute__((address_space(3)))

__device__ __forceinline__ u16 f2b(float x){   // f32 -> bf16 RNE
  u32 u = __float_as_uint(x);
  return (u16)((u + 0x7fffu + ((u >> 16) & 1u)) >> 16);
}

// reduce 4 independent sums across a 256-thread block
__device__ __forceinline__ f4 blockReduce4(f4 v){
  __shared__ f4 s[4];
  int lane = threadIdx.x & 63, w = threadIdx.x >> 6;
#pragma unroll
  for(int o = 32; o; o >>= 1){
    v.x += __shfl_xor(v.x, o);
    v.y += __shfl_xor(v.y, o);
    v.z += __shfl_xor(v.z, o);
    v.w += __shfl_xor(v.w, o);
  }
  if(lane == 0) s[w] = v;
  __syncthreads();
  return s[0] + s[1] + s[2] + s[3];
}

// ---------------- per-layer weight convert + transpose: fp32 [K][N] -> bf16 [N][K] ----------------
struct ConvArgs {
  const float* s0; const float* s1; const float* s2; const float* s3;  // att k,v,r,o [1024][1024]
  const float* skw;  // [1024][4096]
  const float* svw;  // [4096][1024]
  const float* srw;  // [1024][1024]
  u16* dst;          // 13M elems: k@0 v@1M r@2M o@3M fk@4M fv@8M fr@12M
};
__global__ __launch_bounds__(256) void conv_k(ConvArgs a){
  __shared__ __align__(16) u16 t[64][68];
  int b = blockIdx.x, tid = threadIdx.x;
  const float* src; u16* dst; int K, N, tk, tn;
  if(b < 1024){
    int m = b >> 8, bt = b & 255;
    src = (m==0)?a.s0:((m==1)?a.s1:((m==2)?a.s2:a.s3));
    dst = a.dst + (size_t)m*MEG; K=1024; N=1024; tk=bt>>4; tn=bt&15;
  } else if(b < 2048){
    int bt = b-1024; src=a.skw; dst=a.dst+(size_t)4*MEG; K=1024; N=4096; tk=bt>>6; tn=bt&63;
  } else if(b < 3072){
    int bt = b-2048; src=a.svw; dst=a.dst+(size_t)8*MEG; K=4096; N=1024; tk=bt>>4; tn=bt&15;
  } else {
    int bt = b-3072; src=a.srw; dst=a.dst+(size_t)12*MEG; K=1024; N=1024; tk=bt>>4; tn=bt&15;
  }
  int rr0 = tid >> 4, c4 = (tid & 15)*4;
#pragma unroll
  for(int p=0;p<4;p++){
    int r = p*16 + rr0;
    f4 v = *(const f4*)(src + (size_t)(tk*64+r)*N + tn*64 + c4);
    us4 h; h[0]=f2b(v.x); h[1]=f2b(v.y); h[2]=f2b(v.z); h[3]=f2b(v.w);
    *(us4*)&t[r][c4] = h;
  }
  __syncthreads();
  int q = tid & 3, n = tid >> 2;
  int k0 = q*16;
  union { short8 v; u16 h[8]; } o0, o1;
#pragma unroll
  for(int j=0;j<8;j++){ o0.h[j]=t[k0+j][n]; o1.h[j]=t[k0+8+j][n]; }
  u16* dp = dst + (size_t)(tn*64+n)*K + tk*64 + k0;
  *(short8*)dp       = o0.v;
  *(short8*)(dp + 8) = o1.v;
}

// ---------------- embedding + ln0 ----------------
__global__ __launch_bounds__(256) void embed_ln0_k(
    const int* __restrict__ tok, const float* __restrict__ emb,
    const float* __restrict__ w, const float* __restrict__ b,
    float* __restrict__ x){
  int t = blockIdx.x, tid = threadIdx.x;
  const f4* src = (const f4*)(emb + (size_t)tok[t] * Dn);
  f4 v = src[tid];
  f4 st;
  st.x = v.x+v.y+v.z+v.w;
  st.y = v.x*v.x+v.y*v.y+v.z*v.z+v.w*v.w;
  st.z = 0.f; st.w = 0.f;
  f4 red = blockReduce4(st);
  float mu = red.x * (1.0f/Dn);
  float rs = rsqrtf(red.y * (1.0f/Dn) - mu*mu + 1e-5f);
  f4 wv = ((const f4*)w)[tid], bv = ((const f4*)b)[tid];
  f4 o;
  o.x = (v.x-mu)*rs*wv.x + bv.x;
  o.y = (v.y-mu)*rs*wv.y + bv.y;
  o.z = (v.z-mu)*rs*wv.z + bv.z;
  o.w = (v.w-mu)*rs*wv.w + bv.w;
  ((f4*)(x + (size_t)t*Dn))[tid] = o;
}

// ------------- LN + token-shift + mix (attention: k,v,r) -------------
__global__ __launch_bounds__(256) void ln_mix_att_k(
    const float* __restrict__ x,
    const float* __restrict__ lw, const float* __restrict__ lb,
    const float* __restrict__ tk, const float* __restrict__ tv, const float* __restrict__ tr,
    u16* __restrict__ xkvr){
  int t = blockIdx.x, tid = threadIdx.x;
  f4 cur = ((const f4*)(x + (size_t)t*Dn))[tid];
  f4 prv; prv.x=0.f; prv.y=0.f; prv.z=0.f; prv.w=0.f;
  if(t > 0) prv = ((const f4*)(x + (size_t)(t-1)*Dn))[tid];
  f4 st;
  st.x = cur.x+cur.y+cur.z+cur.w;
  st.y = cur.x*cur.x+cur.y*cur.y+cur.z*cur.z+cur.w*cur.w;
  st.z = prv.x+prv.y+prv.z+prv.w;
  st.w = prv.x*prv.x+prv.y*prv.y+prv.z*prv.z+prv.w*prv.w;
  f4 red = blockReduce4(st);
  float muc = red.x*(1.f/Dn), rsc = rsqrtf(red.y*(1.f/Dn)-muc*muc+1e-5f);
  float mup = red.z*(1.f/Dn), rsp = rsqrtf(red.w*(1.f/Dn)-mup*mup+1e-5f);
  f4 wv=((const f4*)lw)[tid], bv=((const f4*)lb)[tid];
  f4 kv=((const f4*)tk)[tid], vv=((const f4*)tv)[tid], rv=((const f4*)tr)[tid];
  us4 ok, ov, orr;
  float xn, xp;
#define MIX3(j, cj, pj, wj, bj, kj, vj, rj) \
  xn = (cj - muc)*rsc*wj + bj; \
  xp = (t>0) ? ((pj - mup)*rsp*wj + bj) : 0.f; \
  ok[j]  = f2b(xn*kj + xp*(1.f-kj)); \
  ov[j]  = f2b(xn*vj + xp*(1.f-vj)); \
  orr[j] = f2b(xn*rj + xp*(1.f-rj));
  MIX3(0, cur.x, prv.x, wv.x, bv.x, kv.x, vv.x, rv.x)
  MIX3(1, cur.y, prv.y, wv.y, bv.y, kv.y, vv.y, rv.y)
  MIX3(2, cur.z, prv.z, wv.z, bv.z, kv.z, vv.z, rv.z)
  MIX3(3, cur.w, prv.w, wv.w, bv.w, kv.w, vv.w, rv.w)
#undef MIX3
  size_t o0 = (size_t)t*Dn + tid*4;
  *(us4*)(xkvr + o0)         = ok;
  *(us4*)(xkvr + TDn + o0)   = ov;
  *(us4*)(xkvr + 2*TDn + o0) = orr;
}

// ------------- LN + token-shift + mix (ffn: k,r) -------------
__global__ __launch_bounds__(256) void ln_mix_ffn_k(
    const float* __restrict__ x,
    const float* __restrict__ lw, const float* __restrict__ lb,
    const float* __restrict__ tk, const float* __restrict__ tr,
    u16* __restrict__ xkr){
  int t = blockIdx.x, tid = threadIdx.x;
  f4 cur = ((const f4*)(x + (size_t)t*Dn))[tid];
  f4 prv; prv.x=0.f; prv.y=0.f; prv.z=0.f; prv.w=0.f;
  if(t > 0) prv = ((const f4*)(x + (size_t)(t-1)*Dn))[tid];
  f4 st;
  st.x = cur.x+cur.y+cur.z+cur.w;
  st.y = cur.x*cur.x+cur.y*cur.y+cur.z*cur.z+cur.w*cur.w;
  st.z = prv.x+prv.y+prv.z+prv.w;
  st.w = prv.x*prv.x+prv.y*prv.y+prv.z*prv.z+prv.w*prv.w;
  f4 red = blockReduce4(st);
  float muc = red.x*(1.f/Dn), rsc = rsqrtf(red.y*(1.f/Dn)-muc*muc+1e-5f);
  float mup = red.z*(1.f/Dn), rsp = rsqrtf(red.w*(1.f/Dn)-mup*mup+1e-5f);
  f4 wv=((const f4*)lw)[tid], bv=((const f4*)lb)[tid];
  f4 kv=((const f4*)tk)[tid], rv=((const f4*)tr)[tid];
  us4 ok, orr;
  float xn, xp;
#define MIX2(j, cj, pj, wj, bj, kj, rj) \
  xn = (cj - muc)*rsc*wj + bj; \
  xp = (t>0) ? ((pj - mup)*rsp*wj + bj) : 0.f; \
  ok[j]  = f2b(xn*kj + xp*(1.f-kj)); \
  orr[j] = f2b(xn*rj + xp*(1.f-rj));
  MIX2(0, cur.x, prv.x, wv.x, bv.x, kv.x, rv.x)
  MIX2(1, cur.y, prv.y, wv.y, bv.y, kv.y, rv.y)
  MIX2(2, cur.z, prv.z, wv.z, bv.z, kv.z, rv.z)
  MIX2(3, cur.w, prv.w, wv.w, bv.w, kv.w, rv.w)
#undef MIX2
  size_t o0 = (size_t)t*Dn + tid*4;
  *(us4*)(xkr + o0)       = ok;
  *(us4*)(xkr + TDn + o0) = orr;
}

// ------------- WKV chunked scan, pass 1 -------------
__global__ __launch_bounds__(256) void wkv_seg_k(
    const float* __restrict__ kb, const float* __restrict__ vb,
    const float* __restrict__ tdp,
    float* __restrict__ sega, float* __restrict__ segb, float* __restrict__ segp){
  int ch = blockIdx.x*256 + threadIdx.x;
  int g = blockIdx.y;
  int t0 = g*SEG;
  float td = tdp[ch];
  float kk[SEG], vv[SEG];
#pragma unroll
  for(int j=0;j<SEG;j++){
    kk[j] = kb[(size_t)(t0+j)*Dn + ch];
    vv[j] = vb[(size_t)(t0+j)*Dn + ch];
  }
  float aa=0.f, bb=0.f, pp=-1e30f;
#pragma unroll
  for(int j=0;j<SEG;j++){
    float ww2 = pp + td;
    float p2 = fmaxf(ww2, kk[j]);
    float e1 = __expf(ww2-p2), e2 = __expf(kk[j]-p2);
    aa = e1*aa + e2*vv[j]; bb = e1*bb + e2; pp = p2;
  }
  size_t o = (size_t)g*Dn + ch;
  sega[o] = aa; segb[o] = bb; segp[o] = pp;
}

// ------------- WKV pass 2: serial compose over segments -------------
__global__ __launch_bounds__(256) void wkv_scan_k(
    const float* __restrict__ sega, const float* __restrict__ segb, const float* __restrict__ segp,
    const float* __restrict__ tdp,
    float* __restrict__ prea, float* __restrict__ preb, float* __restrict__ prep){
  int ch = blockIdx.x*256 + threadIdx.x;
  float Std = tdp[ch] * (float)SEG;
  float a=0.f, b=0.f, p=-1e30f;
  for(int g=0; g<NSEG; g++){
    size_t o = (size_t)g*Dn + ch;
    prea[o]=a; preb[o]=b; prep[o]=p;
    float ag=sega[o], bg=segb[o], qg=segp[o];
    float psh = p + Std;
    float pn = fmaxf(psh, qg);
    float eo = __expf(psh-pn), en = __expf(qg-pn);
    a = eo*a + en*ag; b = eo*b + en*bg; p = pn;
  }
}

// ------------- WKV pass 3: expand from incoming state, fuse sigmoid(r) -------------
__global__ __launch_bounds__(256) void wkv_out_k(
    const float* __restrict__ kb, const float* __restrict__ vb, const float* __restrict__ rb,
    const float* __restrict__ tfp, const float* __restrict__ tdp,
    const float* __restrict__ prea, const float* __restrict__ preb, const float* __restrict__ prep,
    u16* __restrict__ att_in){
  int ch = blockIdx.x*256 + threadIdx.x;
  int g = blockIdx.y;
  int t0 = g*SEG;
  float tf = tfp[ch], td = tdp[ch];
  size_t so = (size_t)g*Dn + ch;
  float aa = prea[so], bb = preb[so], pp = prep[so];
  float kk[SEG], vv[SEG], rr[SEG];
#pragma unroll
  for(int j=0;j<SEG;j++){
    kk[j]=kb[(size_t)(t0+j)*Dn+ch];
    vv[j]=vb[(size_t)(t0+j)*Dn+ch];
    rr[j]=rb[(size_t)(t0+j)*Dn+ch];
  }
#pragma unroll
  for(int j=0;j<SEG;j++){
    float kt=kk[j], vt=vv[j];
    float ww = tf + kt;
    float p = fmaxf(pp, ww);
    float e1 = __expf(pp-p), e2 = __expf(ww-p);
    float out = __fdividef(e1*aa+e2*vt, e1*bb+e2);
    float sig = __fdividef(1.f, 1.f+__expf(-rr[j]));
    att_in[(size_t)(t0+j)*Dn+ch] = f2b(sig*out);
    float ww2 = pp+td;
    float p2 = fmaxf(ww2,kt);
    e1 = __expf(ww2-p2); e2 = __expf(kt-p2);
    aa = e1*aa+e2*vt; bb = e1*bb+e2; pp = p2;
  }
}

// ------------- bf16 GEMM: C[M,N] = A[M,K](bf16,[M][K]) x Bt[N][K](bf16) -------------
// 64x64 tile, WAVES-way split-K within KSTEP, global_load_lds + XOR swizzle, 2-phase dbuf,
// dynamic LDS. WAVES=4 gives 2 waves/SIMD for both the 64KB (2 blocks/CU) and 128KB
// (1 block/CU) LDS configs.
// EPI 0: Cf(+z*strideC) = acc   EPI 1: Cb = bf16(relu(acc)^2)
// EPI 2: Cf += acc              EPI 3: Cf += sigmoid(aux)*acc
template<int EPI, int KSTEP, int WAVES>
__global__ __launch_bounds__(WAVES*64) void gemm_k(
    const u16* __restrict__ A, size_t ldA, size_t strideA,
    const u16* __restrict__ Bt, size_t ldB, size_t strideB,
    int K, int N,
    float* __restrict__ Cf, size_t strideC, u16* __restrict__ Cb,
    const float* __restrict__ aux){
  extern __shared__ __align__(16) u16 ldsd[];     // [2 buf][2 op][64*KSTEP]
  constexpr int RPC = 512/KSTEP;                  // rows per 1KB chunk
  constexpr int LPR = 64/RPC;                     // lanes per row
  constexpr int NCH = KSTEP/8;                    // 1KB chunks per operand tile
  constexpr int NQ  = NCH/WAVES;                  // chunks per wave
  constexpr int WKB = 2*KSTEP/WAVES;              // wave k-window bytes
  constexpr int NS  = WKB/32;                     // MFMA k-slices per wave
  const int tid = threadIdx.x;
  const int l = tid & 63, w = tid >> 6;
  const int z = blockIdx.z;
  const int row0 = blockIdx.y*64, col0 = blockIdx.x*64;

  const u16* bA = A  + (size_t)z*strideA + (size_t)row0*ldA;
  const u16* bB = Bt + (size_t)z*strideB + (size_t)col0*ldB;

  int offA[NQ], offB[NQ], ldso[NQ];
#pragma unroll
  for(int q=0;q<NQ;q++){
    int ch = q*WAVES + w;
    int r  = ch*RPC + l/LPR;
    int phys = (l%LPR)*16;
    int kk = ((phys ^ ((r&15)<<4)) >> 1);
    offA[q] = r*(int)ldA + kk;
    offB[q] = r*(int)ldB + kk;
    ldso[q] = ch*512;
  }
  int foff[2][NS];
#pragma unroll
  for(int i=0;i<2;i++){
    int row = i*32 + (l&31);
#pragma unroll
    for(int s=0;s<NS;s++){
      int c = w*WKB + s*32 + ((l>>5)*16);          // byte within row
      foff[i][s] = row*KSTEP + ((c ^ ((row&15)<<4)) >> 1);
    }
  }

  f32x16 acc[2][2];
#pragma unroll
  for(int i=0;i<2;i++)
#pragma unroll
    for(int j=0;j<2;j++)
#pragma unroll
      for(int e=0;e<16;e++) acc[i][j][e] = 0.f;

  u16* ldsA0 = ldsd;
  u16* ldsB0 = ldsd + 64*KSTEP;
  u16* ldsA1 = ldsd + 2*64*KSTEP;
  u16* ldsB1 = ldsd + 3*64*KSTEP;

#define STAGE(LA, LB) do{ \
  _Pragma("unroll") \
  for(int q=0;q<NQ;q++){ \
    __builtin_amdgcn_global_load_lds((ASG const void*)(const void*)(bA + offA[q]), (ASL void*)(void*)((LA) + ldso[q]), 16, 0, 0); \
    __builtin_amdgcn_global_load_lds((ASG const void*)(const void*)(bB + offB[q]), (ASL void*)(void*)((LB) + ldso[q]), 16, 0, 0); \
  } \
  bA += KSTEP; bB += KSTEP; }while(0)

  const int nss = K / KSTEP;
  STAGE(ldsA0, ldsB0);
  __syncthreads();
  int buf = 0;
  for(int ss=0; ss<nss; ss++){
    if(ss+1 < nss){
      if(buf) STAGE(ldsA0, ldsB0); else STAGE(ldsA1, ldsB1);
    }
    const u16* La = buf ? ldsA1 : ldsA0;
    const u16* Lb = buf ? ldsB1 : ldsB0;
#pragma unroll
    for(int s=0;s<NS;s++){
      short8 a0 = *(const short8*)(La + foff[0][s]);
      short8 a1 = *(const short8*)(La + foff[1][s]);
      short8 b0 = *(const short8*)(Lb + foff[0][s]);
      short8 b1 = *(const short8*)(Lb + foff[1][s]);
      acc[0][0] = __builtin_amdgcn_mfma_f32_32x32x16_bf16(a0, b0, acc[0][0], 0, 0, 0);
      acc[0][1] = __builtin_amdgcn_mfma_f32_32x32x16_bf16(a0, b1, acc[0][1], 0, 0, 0);
      acc[1][0] = __builtin_amdgcn_mfma_f32_32x32x16_bf16(a1, b0, acc[1][0], 0, 0, 0);
      acc[1][1] = __builtin_amdgcn_mfma_f32_32x32x16_bf16(a1, b1, acc[1][1], 0, 0, 0);
    }
    __syncthreads();
    buf ^= 1;
  }
#undef STAGE

  // cross-wave split-K reduction via LDS (waves 1..WAVES-1 -> wave 0), then epilogue
  float* red = (float*)ldsd;
  if(w > 0){
#pragma unroll
    for(int i=0;i<2;i++)
#pragma unroll
      for(int j=0;j<2;j++)
#pragma unroll
        for(int reg=0;reg<16;reg++){
          int rr_ = (reg&3) + 8*(reg>>2) + 4*(l>>5);
          red[(size_t)(w-1)*4096 + (size_t)(i*32 + rr_)*64 + j*32 + (l&31)] = acc[i][j][reg];
        }
  }
  __syncthreads();
  if(w == 0){
#pragma unroll
    for(int i=0;i<2;i++)
#pragma unroll
      for(int j=0;j<2;j++)
#pragma unroll
        for(int reg=0;reg<16;reg++){
          int rr_ = (reg&3) + 8*(reg>>2) + 4*(l>>5);
          size_t lidx = (size_t)(i*32 + rr_)*64 + j*32 + (l&31);
          float v = acc[i][j][reg];
#pragma unroll
          for(int p=0;p<WAVES-1;p++) v += red[(size_t)p*4096 + lidx];
          int grow = row0 + i*32 + rr_;
          int gcol = col0 + j*32 + (l&31);
          size_t idx = (size_t)grow*N + gcol;
          if constexpr(EPI==0){ Cf[(size_t)z*strideC + idx] = v; }
          else if constexpr(EPI==1){ float t_ = v>0.f ? v : 0.f; Cb[idx] = f2b(t_*t_); }
          else if constexpr(EPI==2){ Cf[idx] += v; }
          else { float s_ = __fdividef(1.f, 1.f+__expf(-aux[idx])); Cf[idx] += s_*v; }
        }
  }
}

// ------------- final LN of last row -------------
__global__ __launch_bounds__(256) void lnout_k(
    const float* __restrict__ x, const float* __restrict__ w, const float* __restrict__ b,
    float* __restrict__ xo){
  int tid = threadIdx.x;
  f4 v = ((const f4*)(x + (size_t)(Tn-1)*Dn))[tid];
  f4 st;
  st.x = v.x+v.y+v.z+v.w;
  st.y = v.x*v.x+v.y*v.y+v.z*v.z+v.w*v.w;
  st.z = 0.f; st.w = 0.f;
  f4 red = blockReduce4(st);
  float mu = red.x*(1.f/Dn);
  float rs = rsqrtf(red.y*(1.f/Dn) - mu*mu + 1e-5f);
  f4 wv = ((const f4*)w)[tid], bv = ((const f4*)b)[tid];
  f4 o;
  o.x = (v.x-mu)*rs*wv.x + bv.x;
  o.y = (v.y-mu)*rs*wv.y + bv.y;
  o.z = (v.z-mu)*rs*wv.z + bv.z;
  o.w = (v.w-mu)*rs*wv.w + bv.w;
  ((f4*)xo)[tid] = o;
}

// ------------- head matvec: logits[V] = head[V,D] @ xo[D] -------------
__global__ __launch_bounds__(256) void head_k(
    const float* __restrict__ head, const float* __restrict__ xo, float* __restrict__ out){
  __shared__ f4 sxo[256];
  int tid = threadIdx.x;
  sxo[tid] = ((const f4*)xo)[tid];
  __syncthreads();
  int w = tid >> 6, lane = tid & 63;
  int row = blockIdx.x*4 + w;
  if(row < Vn){
    const f4* hr = (const f4*)(head + (size_t)row*Dn);
    float s = 0.f;
#pragma unroll
    for(int i=0;i<4;i++){
      f4 h = hr[i*64 + lane];
      f4 xv = sxo[i*64 + lane];
      s += h.x*xv.x + h.y*xv.y + h.z*xv.z + h.w*xv.w;
    }
#pragma unroll
    for(int o=32;o;o>>=1) s += __shfl_xor(s, o);
    if(lane == 0) out[row] = s;
  }
}

extern "C" void kernel_launch(void* const* d_in, const int* in_sizes, int n_in,
                              void* d_out, int out_size, void* d_ws, size_t ws_size,
                              hipStream_t stream) {
  (void)in_sizes; (void)n_in; (void)out_size; (void)ws_size;
  const int*   tokens   = (const int*)  d_in[0];
  const float* emb      = (const float*)d_in[1];
  const float* ln0_w    = (const float*)d_in[2];
  const float* ln0_b    = (const float*)d_in[3];
  const float* ln1_w    = (const float*)d_in[4];
  const float* ln1_b    = (const float*)d_in[5];
  const float* ln2_w    = (const float*)d_in[6];
  const float* ln2_b    = (const float*)d_in[7];
  const float* tmk      = (const float*)d_in[8];
  const float* tmv      = (const float*)d_in[9];
  const float* tmr      = (const float*)d_in[10];
  const float* tmk_ffn  = (const float*)d_in[11];
  const float* tmr_ffn  = (const float*)d_in[12];
  const float* tfirst   = (const float*)d_in[13];
  const float* tdecay   = (const float*)d_in[14];
  const float* att_kw   = (const float*)d_in[15];
  const float* att_vw   = (const float*)d_in[16];
  const float* att_rw   = (const float*)d_in[17];
  const float* att_ow   = (const float*)d_in[18];
  const float* ffn_kw   = (const float*)d_in[19];
  const float* ffn_vw   = (const float*)d_in[20];
  const float* ffn_rw   = (const float*)d_in[21];
  const float* lnoutw   = (const float*)d_in[22];
  const float* lnoutb   = (const float*)d_in[23];
  const float* headw    = (const float*)d_in[24];
  float* logits = (float*)d_out;

  char* wsb = (char*)d_ws;
  size_t off = 0;
  auto carve = [&](size_t bytes)->void*{
    void* p = wsb + off;
    off += (bytes + 255) & ~(size_t)255;
    return p;
  };
  float* x      = (float*)carve((size_t)TDn*4);
  u16*   xkvr   = (u16*)  carve((size_t)3*TDn*2);
  float* kvr    = (float*)carve((size_t)3*TDn*4);
  u16*   att_in = (u16*)  carve((size_t)TDn*2);
  u16*   xkr    = (u16*)  carve((size_t)2*TDn*2);
  u16*   kf     = (u16*)  carve((size_t)Tn*F4n*2);
  float* rf     = (float*)carve((size_t)TDn*4);
  float* xo     = (float*)carve((size_t)Dn*4);
  u16*   wbt    = (u16*)  carve((size_t)13*MEG*2);
  float* sega   = (float*)carve((size_t)NSEG*Dn*4);
  float* segb   = (float*)carve((size_t)NSEG*Dn*4);
  float* segp   = (float*)carve((size_t)NSEG*Dn*4);
  float* prea   = (float*)carve((size_t)NSEG*Dn*4);
  float* preb   = (float*)carve((size_t)NSEG*Dn*4);
  float* prep   = (float*)carve((size_t)NSEG*Dn*4);

  embed_ln0_k<<<Tn, 256, 0, stream>>>(tokens, emb, ln0_w, ln0_b, x);

  for(int i=0;i<Ln;i++){
    size_t dd = (size_t)i*Dn*Dn;
    ConvArgs ca;
    ca.s0 = att_kw+dd; ca.s1 = att_vw+dd; ca.s2 = att_rw+dd; ca.s3 = att_ow+dd;
    ca.skw = ffn_kw+(size_t)i*Dn*F4n; ca.svw = ffn_vw+(size_t)i*F4n*Dn; ca.srw = ffn_rw+dd;
    ca.dst = wbt;
    conv_k<<<3328, 256, 0, stream>>>(ca);

    // --- time mix ---
    ln_mix_att_k<<<Tn, 256, 0, stream>>>(x, ln1_w+i*Dn, ln1_b+i*Dn,
                                         tmk+i*Dn, tmv+i*Dn, tmr+i*Dn, xkvr);
    gemm_k<0,128,4><<<dim3(16,16,3), 256, 65536, stream>>>(
        xkvr, Dn, (size_t)TDn, wbt, Dn, (size_t)MEG, Dn, Dn,
        kvr, (size_t)TDn, nullptr, nullptr);
    wkv_seg_k<<<dim3(4,NSEG), 256, 0, stream>>>(kvr, kvr+TDn, tdecay+i*Dn, sega, segb, segp);
    wkv_scan_k<<<4, 256, 0, stream>>>(sega, segb, segp, tdecay+i*Dn, prea, preb, prep);
    wkv_out_k<<<dim3(4,NSEG), 256, 0, stream>>>(kvr, kvr+TDn, kvr+2*TDn,
                                                tfirst+i*Dn, tdecay+i*Dn,
                                                prea, preb, prep, att_in);
    gemm_k<2,256,4><<<dim3(16,16,1), 256, 131072, stream>>>(
        att_in, Dn, 0, wbt+(size_t)3*MEG, Dn, 0, Dn, Dn,
        x, 0, nullptr, nullptr);
    // --- channel mix ---
    ln_mix_ffn_k<<<Tn, 256, 0, stream>>>(x, ln2_w+i*Dn, ln2_b+i*Dn,
                                         tmk_ffn+i*Dn, tmr_ffn+i*Dn, xkr);
    gemm_k<1,128,4><<<dim3(64,16,1), 256, 65536, stream>>>(
        xkr, Dn, 0, wbt+(size_t)4*MEG, Dn, 0, Dn, F4n,
        nullptr, 0, kf, nullptr);
    gemm_k<0,256,4><<<dim3(16,16,1), 256, 131072, stream>>>(
        xkr+TDn, Dn, 0, wbt+(size_t)12*MEG, Dn, 0, Dn, Dn,
        rf, 0, nullptr, nullptr);
    gemm_k<3,256,4><<<dim3(16,16,1), 256, 131072, stream>>>(
        kf, F4n, 0, wbt+(size_t)8*MEG, F4n, 0, F4n, Dn,
        x, 0, nullptr, rf);
  }

  lnout_k<<<1, 256, 0, stream>>>(x, lnoutw, lnoutb, xo);
  head_k<<<(Vn+3)/4, 256, 0, stream>>>(headw, xo, logits);
}

// Round 12
// 1798.596 us; speedup vs baseline: 1.1479x; 1.1479x over previous
//
#include <hip/hip_runtime.h>

#define Tn 1024
#define Dn 1024
#define Ln 12
#define F4n 4096
#define Vn 50277
#define TDn (Tn*Dn)
#define MEG 1048576
#define SEG 16
#define NSEG 64

typedef __attribute__((ext_vector_type(4))) float f4;
typedef __attribute__((ext_vector_type(16))) float f32x16;
typedef __attribute__((ext_vector_type(8))) short short8;
typedef unsigned short u16;
typedef unsigned int u32;
typedef __attribute__((ext_vector_type(4))) u16 us4;

#define ASG __attribute__((address_space(1)))
#define ASL __attribute__((address_space(3)))

__device__ __forceinline__ u16 f2b(float x){   // f32 -> bf16 RNE
  u32 u = __float_as_uint(x);
  return (u16)((u + 0x7fffu + ((u >> 16) & 1u)) >> 16);
}

// reduce 4 independent sums across a 256-thread block
__device__ __forceinline__ f4 blockReduce4(f4 v){
  __shared__ f4 s[4];
  int lane = threadIdx.x & 63, w = threadIdx.x >> 6;
#pragma unroll
  for(int o = 32; o; o >>= 1){
    v.x += __shfl_xor(v.x, o);
    v.y += __shfl_xor(v.y, o);
    v.z += __shfl_xor(v.z, o);
    v.w += __shfl_xor(v.w, o);
  }
  if(lane == 0) s[w] = v;
  __syncthreads();
  return s[0] + s[1] + s[2] + s[3];
}

// ---------------- per-layer weight convert + transpose: fp32 [K][N] -> bf16 [N][K] ----------------
struct ConvArgs {
  const float* s0; const float* s1; const float* s2; const float* s3;  // att k,v,r,o [1024][1024]
  const float* skw;  // [1024][4096]
  const float* svw;  // [4096][1024]
  const float* srw;  // [1024][1024]
  u16* dst;          // 13M elems: k@0 v@1M r@2M o@3M fk@4M fv@8M fr@12M
};
__global__ __launch_bounds__(256) void conv_k(ConvArgs a){
  __shared__ __align__(16) u16 t[64][68];
  int b = blockIdx.x, tid = threadIdx.x;
  const float* src; u16* dst; int K, N, tk, tn;
  if(b < 1024){
    int m = b >> 8, bt = b & 255;
    src = (m==0)?a.s0:((m==1)?a.s1:((m==2)?a.s2:a.s3));
    dst = a.dst + (size_t)m*MEG; K=1024; N=1024; tk=bt>>4; tn=bt&15;
  } else if(b < 2048){
    int bt = b-1024; src=a.skw; dst=a.dst+(size_t)4*MEG; K=1024; N=4096; tk=bt>>6; tn=bt&63;
  } else if(b < 3072){
    int bt = b-2048; src=a.svw; dst=a.dst+(size_t)8*MEG; K=4096; N=1024; tk=bt>>4; tn=bt&15;
  } else {
    int bt = b-3072; src=a.srw; dst=a.dst+(size_t)12*MEG; K=1024; N=1024; tk=bt>>4; tn=bt&15;
  }
  int rr0 = tid >> 4, c4 = (tid & 15)*4;
#pragma unroll
  for(int p=0;p<4;p++){
    int r = p*16 + rr0;
    f4 v = *(const f4*)(src + (size_t)(tk*64+r)*N + tn*64 + c4);
    us4 h; h[0]=f2b(v.x); h[1]=f2b(v.y); h[2]=f2b(v.z); h[3]=f2b(v.w);
    *(us4*)&t[r][c4] = h;
  }
  __syncthreads();
  int q = tid & 3, n = tid >> 2;
  int k0 = q*16;
  union { short8 v; u16 h[8]; } o0, o1;
#pragma unroll
  for(int j=0;j<8;j++){ o0.h[j]=t[k0+j][n]; o1.h[j]=t[k0+8+j][n]; }
  u16* dp = dst + (size_t)(tn*64+n)*K + tk*64 + k0;
  *(short8*)dp       = o0.v;
  *(short8*)(dp + 8) = o1.v;
}

// ---------------- embedding + ln0 ----------------
__global__ __launch_bounds__(256) void embed_ln0_k(
    const int* __restrict__ tok, const float* __restrict__ emb,
    const float* __restrict__ w, const float* __restrict__ b,
    float* __restrict__ x){
  int t = blockIdx.x, tid = threadIdx.x;
  const f4* src = (const f4*)(emb + (size_t)tok[t] * Dn);
  f4 v = src[tid];
  f4 st;
  st.x = v.x+v.y+v.z+v.w;
  st.y = v.x*v.x+v.y*v.y+v.z*v.z+v.w*v.w;
  st.z = 0.f; st.w = 0.f;
  f4 red = blockReduce4(st);
  float mu = red.x * (1.0f/Dn);
  float rs = rsqrtf(red.y * (1.0f/Dn) - mu*mu + 1e-5f);
  f4 wv = ((const f4*)w)[tid], bv = ((const f4*)b)[tid];
  f4 o;
  o.x = (v.x-mu)*rs*wv.x + bv.x;
  o.y = (v.y-mu)*rs*wv.y + bv.y;
  o.z = (v.z-mu)*rs*wv.z + bv.z;
  o.w = (v.w-mu)*rs*wv.w + bv.w;
  ((f4*)(x + (size_t)t*Dn))[tid] = o;
}

// ------------- LN + token-shift + mix (attention: k,v,r) -------------
__global__ __launch_bounds__(256) void ln_mix_att_k(
    const float* __restrict__ x,
    const float* __restrict__ lw, const float* __restrict__ lb,
    const float* __restrict__ tk, const float* __restrict__ tv, const float* __restrict__ tr,
    u16* __restrict__ xkvr){
  int t = blockIdx.x, tid = threadIdx.x;
  f4 cur = ((const f4*)(x + (size_t)t*Dn))[tid];
  f4 prv; prv.x=0.f; prv.y=0.f; prv.z=0.f; prv.w=0.f;
  if(t > 0) prv = ((const f4*)(x + (size_t)(t-1)*Dn))[tid];
  f4 st;
  st.x = cur.x+cur.y+cur.z+cur.w;
  st.y = cur.x*cur.x+cur.y*cur.y+cur.z*cur.z+cur.w*cur.w;
  st.z = prv.x+prv.y+prv.z+prv.w;
  st.w = prv.x*prv.x+prv.y*prv.y+prv.z*prv.z+prv.w*prv.w;
  f4 red = blockReduce4(st);
  float muc = red.x*(1.f/Dn), rsc = rsqrtf(red.y*(1.f/Dn)-muc*muc+1e-5f);
  float mup = red.z*(1.f/Dn), rsp = rsqrtf(red.w*(1.f/Dn)-mup*mup+1e-5f);
  f4 wv=((const f4*)lw)[tid], bv=((const f4*)lb)[tid];
  f4 kv=((const f4*)tk)[tid], vv=((const f4*)tv)[tid], rv=((const f4*)tr)[tid];
  us4 ok, ov, orr;
  float xn, xp;
#define MIX3(j, cj, pj, wj, bj, kj, vj, rj) \
  xn = (cj - muc)*rsc*wj + bj; \
  xp = (t>0) ? ((pj - mup)*rsp*wj + bj) : 0.f; \
  ok[j]  = f2b(xn*kj + xp*(1.f-kj)); \
  ov[j]  = f2b(xn*vj + xp*(1.f-vj)); \
  orr[j] = f2b(xn*rj + xp*(1.f-rj));
  MIX3(0, cur.x, prv.x, wv.x, bv.x, kv.x, vv.x, rv.x)
  MIX3(1, cur.y, prv.y, wv.y, bv.y, kv.y, vv.y, rv.y)
  MIX3(2, cur.z, prv.z, wv.z, bv.z, kv.z, vv.z, rv.z)
  MIX3(3, cur.w, prv.w, wv.w, bv.w, kv.w, vv.w, rv.w)
#undef MIX3
  size_t o0 = (size_t)t*Dn + tid*4;
  *(us4*)(xkvr + o0)         = ok;
  *(us4*)(xkvr + TDn + o0)   = ov;
  *(us4*)(xkvr + 2*TDn + o0) = orr;
}

// ------------- LN + token-shift + mix (ffn: k,r) -------------
__global__ __launch_bounds__(256) void ln_mix_ffn_k(
    const float* __restrict__ x,
    const float* __restrict__ lw, const float* __restrict__ lb,
    const float* __restrict__ tk, const float* __restrict__ tr,
    u16* __restrict__ xkr){
  int t = blockIdx.x, tid = threadIdx.x;
  f4 cur = ((const f4*)(x + (size_t)t*Dn))[tid];
  f4 prv; prv.x=0.f; prv.y=0.f; prv.z=0.f; prv.w=0.f;
  if(t > 0) prv = ((const f4*)(x + (size_t)(t-1)*Dn))[tid];
  f4 st;
  st.x = cur.x+cur.y+cur.z+cur.w;
  st.y = cur.x*cur.x+cur.y*cur.y+cur.z*cur.z+cur.w*cur.w;
  st.z = prv.x+prv.y+prv.z+prv.w;
  st.w = prv.x*prv.x+prv.y*prv.y+prv.z*prv.z+prv.w*prv.w;
  f4 red = blockReduce4(st);
  float muc = red.x*(1.f/Dn), rsc = rsqrtf(red.y*(1.f/Dn)-muc*muc+1e-5f);
  float mup = red.z*(1.f/Dn), rsp = rsqrtf(red.w*(1.f/Dn)-mup*mup+1e-5f);
  f4 wv=((const f4*)lw)[tid], bv=((const f4*)lb)[tid];
  f4 kv=((const f4*)tk)[tid], rv=((const f4*)tr)[tid];
  us4 ok, orr;
  float xn, xp;
#define MIX2(j, cj, pj, wj, bj, kj, rj) \
  xn = (cj - muc)*rsc*wj + bj; \
  xp = (t>0) ? ((pj - mup)*rsp*wj + bj) : 0.f; \
  ok[j]  = f2b(xn*kj + xp*(1.f-kj)); \
  orr[j] = f2b(xn*rj + xp*(1.f-rj));
  MIX2(0, cur.x, prv.x, wv.x, bv.x, kv.x, rv.x)
  MIX2(1, cur.y, prv.y, wv.y, bv.y, kv.y, rv.y)
  MIX2(2, cur.z, prv.z, wv.z, bv.z, kv.z, rv.z)
  MIX2(3, cur.w, prv.w, wv.w, bv.w, kv.w, rv.w)
#undef MIX2
  size_t o0 = (size_t)t*Dn + tid*4;
  *(us4*)(xkr + o0)       = ok;
  *(us4*)(xkr + TDn + o0) = orr;
}

// ------------- WKV chunked scan, pass 1 -------------
__global__ __launch_bounds__(256) void wkv_seg_k(
    const float* __restrict__ kb, const float* __restrict__ vb,
    const float* __restrict__ tdp,
    float* __restrict__ sega, float* __restrict__ segb, float* __restrict__ segp){
  int ch = blockIdx.x*256 + threadIdx.x;
  int g = blockIdx.y;
  int t0 = g*SEG;
  float td = tdp[ch];
  float kk[SEG], vv[SEG];
#pragma unroll
  for(int j=0;j<SEG;j++){
    kk[j] = kb[(size_t)(t0+j)*Dn + ch];
    vv[j] = vb[(size_t)(t0+j)*Dn + ch];
  }
  float aa=0.f, bb=0.f, pp=-1e30f;
#pragma unroll
  for(int j=0;j<SEG;j++){
    float ww2 = pp + td;
    float p2 = fmaxf(ww2, kk[j]);
    float e1 = __expf(ww2-p2), e2 = __expf(kk[j]-p2);
    aa = e1*aa + e2*vv[j]; bb = e1*bb + e2; pp = p2;
  }
  size_t o = (size_t)g*Dn + ch;
  sega[o] = aa; segb[o] = bb; segp[o] = pp;
}

// ------------- WKV pass 2: serial compose over segments -------------
__global__ __launch_bounds__(256) void wkv_scan_k(
    const float* __restrict__ sega, const float* __restrict__ segb, const float* __restrict__ segp,
    const float* __restrict__ tdp,
    float* __restrict__ prea, float* __restrict__ preb, float* __restrict__ prep){
  int ch = blockIdx.x*256 + threadIdx.x;
  float Std = tdp[ch] * (float)SEG;
  float a=0.f, b=0.f, p=-1e30f;
  for(int g=0; g<NSEG; g++){
    size_t o = (size_t)g*Dn + ch;
    prea[o]=a; preb[o]=b; prep[o]=p;
    float ag=sega[o], bg=segb[o], qg=segp[o];
    float psh = p + Std;
    float pn = fmaxf(psh, qg);
    float eo = __expf(psh-pn), en = __expf(qg-pn);
    a = eo*a + en*ag; b = eo*b + en*bg; p = pn;
  }
}

// ------------- WKV pass 3: expand from incoming state, fuse sigmoid(r) -------------
__global__ __launch_bounds__(256) void wkv_out_k(
    const float* __restrict__ kb, const float* __restrict__ vb, const float* __restrict__ rb,
    const float* __restrict__ tfp, const float* __restrict__ tdp,
    const float* __restrict__ prea, const float* __restrict__ preb, const float* __restrict__ prep,
    u16* __restrict__ att_in){
  int ch = blockIdx.x*256 + threadIdx.x;
  int g = blockIdx.y;
  int t0 = g*SEG;
  float tf = tfp[ch], td = tdp[ch];
  size_t so = (size_t)g*Dn + ch;
  float aa = prea[so], bb = preb[so], pp = prep[so];
  float kk[SEG], vv[SEG], rr[SEG];
#pragma unroll
  for(int j=0;j<SEG;j++){
    kk[j]=kb[(size_t)(t0+j)*Dn+ch];
    vv[j]=vb[(size_t)(t0+j)*Dn+ch];
    rr[j]=rb[(size_t)(t0+j)*Dn+ch];
  }
#pragma unroll
  for(int j=0;j<SEG;j++){
    float kt=kk[j], vt=vv[j];
    float ww = tf + kt;
    float p = fmaxf(pp, ww);
    float e1 = __expf(pp-p), e2 = __expf(ww-p);
    float out = __fdividef(e1*aa+e2*vt, e1*bb+e2);
    float sig = __fdividef(1.f, 1.f+__expf(-rr[j]));
    att_in[(size_t)(t0+j)*Dn+ch] = f2b(sig*out);
    float ww2 = pp+td;
    float p2 = fmaxf(ww2,kt);
    e1 = __expf(ww2-p2); e2 = __expf(kt-p2);
    aa = e1*aa+e2*vt; bb = e1*bb+e2; pp = p2;
  }
}

// ------------- bf16 GEMM (R10-proven): 64x64 tile, WAVES-way split-K, dyn LDS -------------
// EPI 0: Cf(+z*strideC) = acc   EPI 1: Cb = bf16(relu(acc)^2)
// EPI 2: Cf += acc              EPI 3: Cf += sigmoid(aux)*acc
template<int EPI, int KSTEP, int WAVES>
__global__ __launch_bounds__(WAVES*64) void gemm_k(
    const u16* __restrict__ A, size_t ldA, size_t strideA,
    const u16* __restrict__ Bt, size_t ldB, size_t strideB,
    int K, int N,
    float* __restrict__ Cf, size_t strideC, u16* __restrict__ Cb,
    const float* __restrict__ aux){
  extern __shared__ __align__(16) u16 ldsd[];     // [2 buf][2 op][64*KSTEP]
  constexpr int RPC = 512/KSTEP;
  constexpr int LPR = 64/RPC;
  constexpr int NCH = KSTEP/8;
  constexpr int NQ  = NCH/WAVES;
  constexpr int WKB = 2*KSTEP/WAVES;
  constexpr int NS  = WKB/32;
  const int tid = threadIdx.x;
  const int l = tid & 63, w = tid >> 6;
  const int z = blockIdx.z;
  const int row0 = blockIdx.y*64, col0 = blockIdx.x*64;

  const u16* bA = A  + (size_t)z*strideA + (size_t)row0*ldA;
  const u16* bB = Bt + (size_t)z*strideB + (size_t)col0*ldB;

  int offA[NQ], offB[NQ], ldso[NQ];
#pragma unroll
  for(int q=0;q<NQ;q++){
    int ch = q*WAVES + w;
    int r  = ch*RPC + l/LPR;
    int phys = (l%LPR)*16;
    int kk = ((phys ^ ((r&15)<<4)) >> 1);
    offA[q] = r*(int)ldA + kk;
    offB[q] = r*(int)ldB + kk;
    ldso[q] = ch*512;
  }
  int foff[2][NS];
#pragma unroll
  for(int i=0;i<2;i++){
    int row = i*32 + (l&31);
#pragma unroll
    for(int s=0;s<NS;s++){
      int c = w*WKB + s*32 + ((l>>5)*16);
      foff[i][s] = row*KSTEP + ((c ^ ((row&15)<<4)) >> 1);
    }
  }

  f32x16 acc[2][2];
#pragma unroll
  for(int i=0;i<2;i++)
#pragma unroll
    for(int j=0;j<2;j++)
#pragma unroll
      for(int e=0;e<16;e++) acc[i][j][e] = 0.f;

  u16* ldsA0 = ldsd;
  u16* ldsB0 = ldsd + 64*KSTEP;
  u16* ldsA1 = ldsd + 2*64*KSTEP;
  u16* ldsB1 = ldsd + 3*64*KSTEP;

#define STAGE(LA, LB) do{ \
  _Pragma("unroll") \
  for(int q=0;q<NQ;q++){ \
    __builtin_amdgcn_global_load_lds((ASG const void*)(const void*)(bA + offA[q]), (ASL void*)(void*)((LA) + ldso[q]), 16, 0, 0); \
    __builtin_amdgcn_global_load_lds((ASG const void*)(const void*)(bB + offB[q]), (ASL void*)(void*)((LB) + ldso[q]), 16, 0, 0); \
  } \
  bA += KSTEP; bB += KSTEP; }while(0)

  const int nss = K / KSTEP;
  STAGE(ldsA0, ldsB0);
  __syncthreads();
  int buf = 0;
  for(int ss=0; ss<nss; ss++){
    if(ss+1 < nss){
      if(buf) STAGE(ldsA0, ldsB0); else STAGE(ldsA1, ldsB1);
    }
    const u16* La = buf ? ldsA1 : ldsA0;
    const u16* Lb = buf ? ldsB1 : ldsB0;
#pragma unroll
    for(int s=0;s<NS;s++){
      short8 a0 = *(const short8*)(La + foff[0][s]);
      short8 a1 = *(const short8*)(La + foff[1][s]);
      short8 b0 = *(const short8*)(Lb + foff[0][s]);
      short8 b1 = *(const short8*)(Lb + foff[1][s]);
      acc[0][0] = __builtin_amdgcn_mfma_f32_32x32x16_bf16(a0, b0, acc[0][0], 0, 0, 0);
      acc[0][1] = __builtin_amdgcn_mfma_f32_32x32x16_bf16(a0, b1, acc[0][1], 0, 0, 0);
      acc[1][0] = __builtin_amdgcn_mfma_f32_32x32x16_bf16(a1, b0, acc[1][0], 0, 0, 0);
      acc[1][1] = __builtin_amdgcn_mfma_f32_32x32x16_bf16(a1, b1, acc[1][1], 0, 0, 0);
    }
    __syncthreads();
    buf ^= 1;
  }
#undef STAGE

  float* red = (float*)ldsd;
  if(w > 0){
#pragma unroll
    for(int i=0;i<2;i++)
#pragma unroll
      for(int j=0;j<2;j++)
#pragma unroll
        for(int reg=0;reg<16;reg++){
          int rr_ = (reg&3) + 8*(reg>>2) + 4*(l>>5);
          red[(size_t)(w-1)*4096 + (size_t)(i*32 + rr_)*64 + j*32 + (l&31)] = acc[i][j][reg];
        }
  }
  __syncthreads();
  if(w == 0){
#pragma unroll
    for(int i=0;i<2;i++)
#pragma unroll
      for(int j=0;j<2;j++)
#pragma unroll
        for(int reg=0;reg<16;reg++){
          int rr_ = (reg&3) + 8*(reg>>2) + 4*(l>>5);
          size_t lidx = (size_t)(i*32 + rr_)*64 + j*32 + (l&31);
          float v = acc[i][j][reg];
#pragma unroll
          for(int p=0;p<WAVES-1;p++) v += red[(size_t)p*4096 + lidx];
          int grow = row0 + i*32 + rr_;
          int gcol = col0 + j*32 + (l&31);
          size_t idx = (size_t)grow*N + gcol;
          if constexpr(EPI==0){ Cf[(size_t)z*strideC + idx] = v; }
          else if constexpr(EPI==1){ float t_ = v>0.f ? v : 0.f; Cb[idx] = f2b(t_*t_); }
          else if constexpr(EPI==2){ Cf[idx] += v; }
          else { float s_ = __fdividef(1.f, 1.f+__expf(-aux[idx])); Cf[idx] += s_*v; }
        }
  }
}

// ------------- FFN-k GEMM, 128x128 tile: kf = bf16(relu(xkr @ fkw)^2) -------------
// KSTEP=64, 4 waves in 2x2 quadrants (each wave owns a 64x64 output quadrant, no reduce),
// 64 KB LDS (2 blocks/CU), global_load_lds + 8-slot XOR swizzle. Grid (N/128, M/128) = (32,8).
__global__ __launch_bounds__(256) void gemm_fk_k(
    const u16* __restrict__ A,   // xkr [1024][1024]
    const u16* __restrict__ Bt,  // fkw^T [4096][1024]
    u16* __restrict__ Cb){       // kf [1024][4096]
  extern __shared__ __align__(16) u16 ldsd[];   // [2 buf][A 128x64 | B 128x64] = 64 KB
  constexpr int KS = 64;                         // KSTEP elems
  const int tid = threadIdx.x;
  const int l = tid & 63, w = tid >> 6;
  const int wm = (w>>1)*64, wn = (w&1)*64;       // wave quadrant
  const int row0 = blockIdx.y*128, col0 = blockIdx.x*128;

  const u16* bA = A  + (size_t)row0*Dn;
  const u16* bB = Bt + (size_t)col0*Dn;

  // staging: per operand 128 rows x 128 B = 16 chunks of 1 KB; wave w owns chunks q*4+w.
  // chunk ch: row r = ch*8 + (l>>3); phys byte (l&7)*16; src pre-swizzled by ((r&7)<<4).
  int offA[4], offB[4], ldso[4];
#pragma unroll
  for(int q=0;q<4;q++){
    int ch = q*4 + w;
    int r  = ch*8 + (l>>3);
    int kk = ((((l&7)*16) ^ ((l>>3)<<4)) >> 1);
    offA[q] = r*Dn + kk;
    offB[q] = r*Dn + kk;
    ldso[q] = ch*512;                            // u16 elems
  }
  // fragment reads: rows (quadrant-local), 4 k-slices of 32 B; swizzle key (row&7)<<4
  int foffA[2][4], foffB[2][4];
#pragma unroll
  for(int i=0;i<2;i++){
    int ar = wm + i*32 + (l&31);
    int br = wn + i*32 + (l&31);
#pragma unroll
    for(int s=0;s<4;s++){
      int c = s*32 + ((l>>5)*16);
      foffA[i][s] = ar*KS + ((c ^ ((ar&7)<<4)) >> 1);
      foffB[i][s] = br*KS + ((c ^ ((br&7)<<4)) >> 1);
    }
  }

  f32x16 acc[2][2];
#pragma unroll
  for(int i=0;i<2;i++)
#pragma unroll
    for(int j=0;j<2;j++)
#pragma unroll
      for(int e=0;e<16;e++) acc[i][j][e] = 0.f;

  u16* ldsA0 = ldsd;                 // 128*64 = 8192 u16 = 16 KB
  u16* ldsB0 = ldsd + 8192;
  u16* ldsA1 = ldsd + 16384;
  u16* ldsB1 = ldsd + 24576;

#define STAGE(LA, LB) do{ \
  _Pragma("unroll") \
  for(int q=0;q<4;q++){ \
    __builtin_amdgcn_global_load_lds((ASG const void*)(const void*)(bA + offA[q]), (ASL void*)(void*)((LA) + ldso[q]), 16, 0, 0); \
    __builtin_amdgcn_global_load_lds((ASG const void*)(const void*)(bB + offB[q]), (ASL void*)(void*)((LB) + ldso[q]), 16, 0, 0); \
  } \
  bA += KS; bB += KS; }while(0)

  STAGE(ldsA0, ldsB0);
  __syncthreads();
  int buf = 0;
#pragma unroll 1
  for(int ss=0; ss<16; ss++){        // K=1024 / 64
    if(ss+1 < 16){
      if(buf) STAGE(ldsA0, ldsB0); else STAGE(ldsA1, ldsB1);
    }
    const u16* La = buf ? ldsA1 : ldsA0;
    const u16* Lb = buf ? ldsB1 : ldsB0;
#pragma unroll
    for(int s=0;s<4;s++){
      short8 a0 = *(const short8*)(La + foffA[0][s]);
      short8 a1 = *(const short8*)(La + foffA[1][s]);
      short8 b0 = *(const short8*)(Lb + foffB[0][s]);
      short8 b1 = *(const short8*)(Lb + foffB[1][s]);
      acc[0][0] = __builtin_amdgcn_mfma_f32_32x32x16_bf16(a0, b0, acc[0][0], 0, 0, 0);
      acc[0][1] = __builtin_amdgcn_mfma_f32_32x32x16_bf16(a0, b1, acc[0][1], 0, 0, 0);
      acc[1][0] = __builtin_amdgcn_mfma_f32_32x32x16_bf16(a1, b0, acc[1][0], 0, 0, 0);
      acc[1][1] = __builtin_amdgcn_mfma_f32_32x32x16_bf16(a1, b1, acc[1][1], 0, 0, 0);
    }
    __syncthreads();
    buf ^= 1;
  }
#undef STAGE

  // epilogue: each wave writes its own quadrant (no reduce)
#pragma unroll
  for(int i=0;i<2;i++){
#pragma unroll
    for(int j=0;j<2;j++){
#pragma unroll
      for(int reg=0;reg<16;reg++){
        int rr_ = (reg&3) + 8*(reg>>2) + 4*(l>>5);
        int grow = row0 + wm + i*32 + rr_;
        int gcol = col0 + wn + j*32 + (l&31);
        float v = acc[i][j][reg];
        float t_ = v>0.f ? v : 0.f;
        Cb[(size_t)grow*F4n + gcol] = f2b(t_*t_);
      }
    }
  }
}

// ------------- final LN of last row -------------
__global__ __launch_bounds__(256) void lnout_k(
    const float* __restrict__ x, const float* __restrict__ w, const float* __restrict__ b,
    float* __restrict__ xo){
  int tid = threadIdx.x;
  f4 v = ((const f4*)(x + (size_t)(Tn-1)*Dn))[tid];
  f4 st;
  st.x = v.x+v.y+v.z+v.w;
  st.y = v.x*v.x+v.y*v.y+v.z*v.z+v.w*v.w;
  st.z = 0.f; st.w = 0.f;
  f4 red = blockReduce4(st);
  float mu = red.x*(1.f/Dn);
  float rs = rsqrtf(red.y*(1.f/Dn) - mu*mu + 1e-5f);
  f4 wv = ((const f4*)w)[tid], bv = ((const f4*)b)[tid];
  f4 o;
  o.x = (v.x-mu)*rs*wv.x + bv.x;
  o.y = (v.y-mu)*rs*wv.y + bv.y;
  o.z = (v.z-mu)*rs*wv.z + bv.z;
  o.w = (v.w-mu)*rs*wv.w + bv.w;
  ((f4*)xo)[tid] = o;
}

// ------------- head matvec: logits[V] = head[V,D] @ xo[D] -------------
__global__ __launch_bounds__(256) void head_k(
    const float* __restrict__ head, const float* __restrict__ xo, float* __restrict__ out){
  __shared__ f4 sxo[256];
  int tid = threadIdx.x;
  sxo[tid] = ((const f4*)xo)[tid];
  __syncthreads();
  int w = tid >> 6, lane = tid & 63;
  int row = blockIdx.x*4 + w;
  if(row < Vn){
    const f4* hr = (const f4*)(head + (size_t)row*Dn);
    float s = 0.f;
#pragma unroll
    for(int i=0;i<4;i++){
      f4 h = hr[i*64 + lane];
      f4 xv = sxo[i*64 + lane];
      s += h.x*xv.x + h.y*xv.y + h.z*xv.z + h.w*xv.w;
    }
#pragma unroll
    for(int o=32;o;o>>=1) s += __shfl_xor(s, o);
    if(lane == 0) out[row] = s;
  }
}

extern "C" void kernel_launch(void* const* d_in, const int* in_sizes, int n_in,
                              void* d_out, int out_size, void* d_ws, size_t ws_size,
                              hipStream_t stream) {
  (void)in_sizes; (void)n_in; (void)out_size; (void)ws_size;
  const int*   tokens   = (const int*)  d_in[0];
  const float* emb      = (const float*)d_in[1];
  const float* ln0_w    = (const float*)d_in[2];
  const float* ln0_b    = (const float*)d_in[3];
  const float* ln1_w    = (const float*)d_in[4];
  const float* ln1_b    = (const float*)d_in[5];
  const float* ln2_w    = (const float*)d_in[6];
  const float* ln2_b    = (const float*)d_in[7];
  const float* tmk      = (const float*)d_in[8];
  const float* tmv      = (const float*)d_in[9];
  const float* tmr      = (const float*)d_in[10];
  const float* tmk_ffn  = (const float*)d_in[11];
  const float* tmr_ffn  = (const float*)d_in[12];
  const float* tfirst   = (const float*)d_in[13];
  const float* tdecay   = (const float*)d_in[14];
  const float* att_kw   = (const float*)d_in[15];
  const float* att_vw   = (const float*)d_in[16];
  const float* att_rw   = (const float*)d_in[17];
  const float* att_ow   = (const float*)d_in[18];
  const float* ffn_kw   = (const float*)d_in[19];
  const float* ffn_vw   = (const float*)d_in[20];
  const float* ffn_rw   = (const float*)d_in[21];
  const float* lnoutw   = (const float*)d_in[22];
  const float* lnoutb   = (const float*)d_in[23];
  const float* headw    = (const float*)d_in[24];
  float* logits = (float*)d_out;

  char* wsb = (char*)d_ws;
  size_t off = 0;
  auto carve = [&](size_t bytes)->void*{
    void* p = wsb + off;
    off += (bytes + 255) & ~(size_t)255;
    return p;
  };
  float* x      = (float*)carve((size_t)TDn*4);
  u16*   xkvr   = (u16*)  carve((size_t)3*TDn*2);
  float* kvr    = (float*)carve((size_t)3*TDn*4);
  u16*   att_in = (u16*)  carve((size_t)TDn*2);
  u16*   xkr    = (u16*)  carve((size_t)2*TDn*2);
  u16*   kf     = (u16*)  carve((size_t)Tn*F4n*2);
  float* rf     = (float*)carve((size_t)TDn*4);
  float* xo     = (float*)carve((size_t)Dn*4);
  u16*   wbt    = (u16*)  carve((size_t)13*MEG*2);
  float* sega   = (float*)carve((size_t)NSEG*Dn*4);
  float* segb   = (float*)carve((size_t)NSEG*Dn*4);
  float* segp   = (float*)carve((size_t)NSEG*Dn*4);
  float* prea   = (float*)carve((size_t)NSEG*Dn*4);
  float* preb   = (float*)carve((size_t)NSEG*Dn*4);
  float* prep   = (float*)carve((size_t)NSEG*Dn*4);

  embed_ln0_k<<<Tn, 256, 0, stream>>>(tokens, emb, ln0_w, ln0_b, x);

  for(int i=0;i<Ln;i++){
    size_t dd = (size_t)i*Dn*Dn;
    ConvArgs ca;
    ca.s0 = att_kw+dd; ca.s1 = att_vw+dd; ca.s2 = att_rw+dd; ca.s3 = att_ow+dd;
    ca.skw = ffn_kw+(size_t)i*Dn*F4n; ca.svw = ffn_vw+(size_t)i*F4n*Dn; ca.srw = ffn_rw+dd;
    ca.dst = wbt;
    conv_k<<<3328, 256, 0, stream>>>(ca);

    // --- time mix ---
    ln_mix_att_k<<<Tn, 256, 0, stream>>>(x, ln1_w+i*Dn, ln1_b+i*Dn,
                                         tmk+i*Dn, tmv+i*Dn, tmr+i*Dn, xkvr);
    gemm_k<0,128,2><<<dim3(16,16,3), 128, 65536, stream>>>(
        xkvr, Dn, (size_t)TDn, wbt, Dn, (size_t)MEG, Dn, Dn,
        kvr, (size_t)TDn, nullptr, nullptr);
    wkv_seg_k<<<dim3(4,NSEG), 256, 0, stream>>>(kvr, kvr+TDn, tdecay+i*Dn, sega, segb, segp);
    wkv_scan_k<<<4, 256, 0, stream>>>(sega, segb, segp, tdecay+i*Dn, prea, preb, prep);
    wkv_out_k<<<dim3(4,NSEG), 256, 0, stream>>>(kvr, kvr+TDn, kvr+2*TDn,
                                                tfirst+i*Dn, tdecay+i*Dn,
                                                prea, preb, prep, att_in);
    gemm_k<2,256,4><<<dim3(16,16,1), 256, 131072, stream>>>(
        att_in, Dn, 0, wbt+(size_t)3*MEG, Dn, 0, Dn, Dn,
        x, 0, nullptr, nullptr);
    // --- channel mix ---
    ln_mix_ffn_k<<<Tn, 256, 0, stream>>>(x, ln2_w+i*Dn, ln2_b+i*Dn,
                                         tmk_ffn+i*Dn, tmr_ffn+i*Dn, xkr);
    gemm_fk_k<<<dim3(32,8), 256, 65536, stream>>>(xkr, wbt+(size_t)4*MEG, kf);
    gemm_k<0,256,4><<<dim3(16,16,1), 256, 131072, stream>>>(
        xkr+TDn, Dn, 0, wbt+(size_t)12*MEG, Dn, 0, Dn, Dn,
        rf, 0, nullptr, nullptr);
    gemm_k<3,256,4><<<dim3(16,16,1), 256, 131072, stream>>>(
        kf, F4n, 0, wbt+(size_t)8*MEG, F4n, 0, F4n, Dn,
        x, 0, nullptr, rf);
  }

  lnout_k<<<1, 256, 0, stream>>>(x, lnoutw, lnoutb, xo);
  head_k<<<(Vn+3)/4, 256, 0, stream>>>(headw, xo, logits);
}

// Round 13
// 1757.633 us; speedup vs baseline: 1.1746x; 1.0233x over previous
//
#include <hip/hip_runtime.h>

#define Tn 1024
#define Dn 1024
#define Ln 12
#define F4n 4096
#define Vn 50277
#define TDn (Tn*Dn)
#define MEG 1048576
#define SEG 16
#define NSEG 64

typedef __attribute__((ext_vector_type(4))) float f4;
typedef __attribute__((ext_vector_type(16))) float f32x16;
typedef __attribute__((ext_vector_type(8))) short short8;
typedef unsigned short u16;
typedef unsigned int u32;
typedef __attribute__((ext_vector_type(4))) u16 us4;

#define ASG __attribute__((address_space(1)))
#define ASL __attribute__((address_space(3)))

__device__ __forceinline__ u16 f2b(float x){   // f32 -> bf16 RNE
  u32 u = __float_as_uint(x);
  return (u16)((u + 0x7fffu + ((u >> 16) & 1u)) >> 16);
}

// reduce 4 independent sums across a 256-thread block
__device__ __forceinline__ f4 blockReduce4(f4 v){
  __shared__ f4 s[4];
  int lane = threadIdx.x & 63, w = threadIdx.x >> 6;
#pragma unroll
  for(int o = 32; o; o >>= 1){
    v.x += __shfl_xor(v.x, o);
    v.y += __shfl_xor(v.y, o);
    v.z += __shfl_xor(v.z, o);
    v.w += __shfl_xor(v.w, o);
  }
  if(lane == 0) s[w] = v;
  __syncthreads();
  return s[0] + s[1] + s[2] + s[3];
}

// ---------------- per-layer weight convert + transpose: fp32 [K][N] -> bf16 [N][K] ----------------
struct ConvArgs {
  const float* s0; const float* s1; const float* s2; const float* s3;  // att k,v,r,o [1024][1024]
  const float* skw;  // [1024][4096]
  const float* svw;  // [4096][1024]
  const float* srw;  // [1024][1024]
  u16* dst;          // 13M elems: k@0 v@1M r@2M o@3M fk@4M fv@8M fr@12M
};
__global__ __launch_bounds__(256) void conv_k(ConvArgs a){
  __shared__ __align__(16) u16 t[64][68];
  int b = blockIdx.x, tid = threadIdx.x;
  const float* src; u16* dst; int K, N, tk, tn;
  if(b < 1024){
    int m = b >> 8, bt = b & 255;
    src = (m==0)?a.s0:((m==1)?a.s1:((m==2)?a.s2:a.s3));
    dst = a.dst + (size_t)m*MEG; K=1024; N=1024; tk=bt>>4; tn=bt&15;
  } else if(b < 2048){
    int bt = b-1024; src=a.skw; dst=a.dst+(size_t)4*MEG; K=1024; N=4096; tk=bt>>6; tn=bt&63;
  } else if(b < 3072){
    int bt = b-2048; src=a.svw; dst=a.dst+(size_t)8*MEG; K=4096; N=1024; tk=bt>>4; tn=bt&15;
  } else {
    int bt = b-3072; src=a.srw; dst=a.dst+(size_t)12*MEG; K=1024; N=1024; tk=bt>>4; tn=bt&15;
  }
  int rr0 = tid >> 4, c4 = (tid & 15)*4;
#pragma unroll
  for(int p=0;p<4;p++){
    int r = p*16 + rr0;
    f4 v = *(const f4*)(src + (size_t)(tk*64+r)*N + tn*64 + c4);
    us4 h; h[0]=f2b(v.x); h[1]=f2b(v.y); h[2]=f2b(v.z); h[3]=f2b(v.w);
    *(us4*)&t[r][c4] = h;
  }
  __syncthreads();
  int q = tid & 3, n = tid >> 2;
  int k0 = q*16;
  union { short8 v; u16 h[8]; } o0, o1;
#pragma unroll
  for(int j=0;j<8;j++){ o0.h[j]=t[k0+j][n]; o1.h[j]=t[k0+8+j][n]; }
  u16* dp = dst + (size_t)(tn*64+n)*K + tk*64 + k0;
  *(short8*)dp       = o0.v;
  *(short8*)(dp + 8) = o1.v;
}

// ---------------- embedding + ln0 ----------------
__global__ __launch_bounds__(256) void embed_ln0_k(
    const int* __restrict__ tok, const float* __restrict__ emb,
    const float* __restrict__ w, const float* __restrict__ b,
    float* __restrict__ x){
  int t = blockIdx.x, tid = threadIdx.x;
  const f4* src = (const f4*)(emb + (size_t)tok[t] * Dn);
  f4 v = src[tid];
  f4 st;
  st.x = v.x+v.y+v.z+v.w;
  st.y = v.x*v.x+v.y*v.y+v.z*v.z+v.w*v.w;
  st.z = 0.f; st.w = 0.f;
  f4 red = blockReduce4(st);
  float mu = red.x * (1.0f/Dn);
  float rs = rsqrtf(red.y * (1.0f/Dn) - mu*mu + 1e-5f);
  f4 wv = ((const f4*)w)[tid], bv = ((const f4*)b)[tid];
  f4 o;
  o.x = (v.x-mu)*rs*wv.x + bv.x;
  o.y = (v.y-mu)*rs*wv.y + bv.y;
  o.z = (v.z-mu)*rs*wv.z + bv.z;
  o.w = (v.w-mu)*rs*wv.w + bv.w;
  ((f4*)(x + (size_t)t*Dn))[tid] = o;
}

// ------------- LN + token-shift + mix (attention: k,v,r) -------------
__global__ __launch_bounds__(256) void ln_mix_att_k(
    const float* __restrict__ x,
    const float* __restrict__ lw, const float* __restrict__ lb,
    const float* __restrict__ tk, const float* __restrict__ tv, const float* __restrict__ tr,
    u16* __restrict__ xkvr){
  int t = blockIdx.x, tid = threadIdx.x;
  f4 cur = ((const f4*)(x + (size_t)t*Dn))[tid];
  f4 prv; prv.x=0.f; prv.y=0.f; prv.z=0.f; prv.w=0.f;
  if(t > 0) prv = ((const f4*)(x + (size_t)(t-1)*Dn))[tid];
  f4 st;
  st.x = cur.x+cur.y+cur.z+cur.w;
  st.y = cur.x*cur.x+cur.y*cur.y+cur.z*cur.z+cur.w*cur.w;
  st.z = prv.x+prv.y+prv.z+prv.w;
  st.w = prv.x*prv.x+prv.y*prv.y+prv.z*prv.z+prv.w*prv.w;
  f4 red = blockReduce4(st);
  float muc = red.x*(1.f/Dn), rsc = rsqrtf(red.y*(1.f/Dn)-muc*muc+1e-5f);
  float mup = red.z*(1.f/Dn), rsp = rsqrtf(red.w*(1.f/Dn)-mup*mup+1e-5f);
  f4 wv=((const f4*)lw)[tid], bv=((const f4*)lb)[tid];
  f4 kv=((const f4*)tk)[tid], vv=((const f4*)tv)[tid], rv=((const f4*)tr)[tid];
  us4 ok, ov, orr;
  float xn, xp;
#define MIX3(j, cj, pj, wj, bj, kj, vj, rj) \
  xn = (cj - muc)*rsc*wj + bj; \
  xp = (t>0) ? ((pj - mup)*rsp*wj + bj) : 0.f; \
  ok[j]  = f2b(xn*kj + xp*(1.f-kj)); \
  ov[j]  = f2b(xn*vj + xp*(1.f-vj)); \
  orr[j] = f2b(xn*rj + xp*(1.f-rj));
  MIX3(0, cur.x, prv.x, wv.x, bv.x, kv.x, vv.x, rv.x)
  MIX3(1, cur.y, prv.y, wv.y, bv.y, kv.y, vv.y, rv.y)
  MIX3(2, cur.z, prv.z, wv.z, bv.z, kv.z, vv.z, rv.z)
  MIX3(3, cur.w, prv.w, wv.w, bv.w, kv.w, vv.w, rv.w)
#undef MIX3
  size_t o0 = (size_t)t*Dn + tid*4;
  *(us4*)(xkvr + o0)         = ok;
  *(us4*)(xkvr + TDn + o0)   = ov;
  *(us4*)(xkvr + 2*TDn + o0) = orr;
}

// ------------- LN + token-shift + mix (ffn: k,r) -------------
__global__ __launch_bounds__(256) void ln_mix_ffn_k(
    const float* __restrict__ x,
    const float* __restrict__ lw, const float* __restrict__ lb,
    const float* __restrict__ tk, const float* __restrict__ tr,
    u16* __restrict__ xkr){
  int t = blockIdx.x, tid = threadIdx.x;
  f4 cur = ((const f4*)(x + (size_t)t*Dn))[tid];
  f4 prv; prv.x=0.f; prv.y=0.f; prv.z=0.f; prv.w=0.f;
  if(t > 0) prv = ((const f4*)(x + (size_t)(t-1)*Dn))[tid];
  f4 st;
  st.x = cur.x+cur.y+cur.z+cur.w;
  st.y = cur.x*cur.x+cur.y*cur.y+cur.z*cur.z+cur.w*cur.w;
  st.z = prv.x+prv.y+prv.z+prv.w;
  st.w = prv.x*prv.x+prv.y*prv.y+prv.z*prv.z+prv.w*prv.w;
  f4 red = blockReduce4(st);
  float muc = red.x*(1.f/Dn), rsc = rsqrtf(red.y*(1.f/Dn)-muc*muc+1e-5f);
  float mup = red.z*(1.f/Dn), rsp = rsqrtf(red.w*(1.f/Dn)-mup*mup+1e-5f);
  f4 wv=((const f4*)lw)[tid], bv=((const f4*)lb)[tid];
  f4 kv=((const f4*)tk)[tid], rv=((const f4*)tr)[tid];
  us4 ok, orr;
  float xn, xp;
#define MIX2(j, cj, pj, wj, bj, kj, rj) \
  xn = (cj - muc)*rsc*wj + bj; \
  xp = (t>0) ? ((pj - mup)*rsp*wj + bj) : 0.f; \
  ok[j]  = f2b(xn*kj + xp*(1.f-kj)); \
  orr[j] = f2b(xn*rj + xp*(1.f-rj));
  MIX2(0, cur.x, prv.x, wv.x, bv.x, kv.x, rv.x)
  MIX2(1, cur.y, prv.y, wv.y, bv.y, kv.y, rv.y)
  MIX2(2, cur.z, prv.z, wv.z, bv.z, kv.z, rv.z)
  MIX2(3, cur.w, prv.w, wv.w, bv.w, kv.w, rv.w)
#undef MIX2
  size_t o0 = (size_t)t*Dn + tid*4;
  *(us4*)(xkr + o0)       = ok;
  *(us4*)(xkr + TDn + o0) = orr;
}

// ------------- WKV chunked scan, pass 1 -------------
__global__ __launch_bounds__(256) void wkv_seg_k(
    const float* __restrict__ kb, const float* __restrict__ vb,
    const float* __restrict__ tdp,
    float* __restrict__ sega, float* __restrict__ segb, float* __restrict__ segp){
  int ch = blockIdx.x*256 + threadIdx.x;
  int g = blockIdx.y;
  int t0 = g*SEG;
  float td = tdp[ch];
  float kk[SEG], vv[SEG];
#pragma unroll
  for(int j=0;j<SEG;j++){
    kk[j] = kb[(size_t)(t0+j)*Dn + ch];
    vv[j] = vb[(size_t)(t0+j)*Dn + ch];
  }
  float aa=0.f, bb=0.f, pp=-1e30f;
#pragma unroll
  for(int j=0;j<SEG;j++){
    float ww2 = pp + td;
    float p2 = fmaxf(ww2, kk[j]);
    float e1 = __expf(ww2-p2), e2 = __expf(kk[j]-p2);
    aa = e1*aa + e2*vv[j]; bb = e1*bb + e2; pp = p2;
  }
  size_t o = (size_t)g*Dn + ch;
  sega[o] = aa; segb[o] = bb; segp[o] = pp;
}

// ------------- WKV pass 2: serial compose over segments -------------
__global__ __launch_bounds__(256) void wkv_scan_k(
    const float* __restrict__ sega, const float* __restrict__ segb, const float* __restrict__ segp,
    const float* __restrict__ tdp,
    float* __restrict__ prea, float* __restrict__ preb, float* __restrict__ prep){
  int ch = blockIdx.x*256 + threadIdx.x;
  float Std = tdp[ch] * (float)SEG;
  float a=0.f, b=0.f, p=-1e30f;
  for(int g=0; g<NSEG; g++){
    size_t o = (size_t)g*Dn + ch;
    prea[o]=a; preb[o]=b; prep[o]=p;
    float ag=sega[o], bg=segb[o], qg=segp[o];
    float psh = p + Std;
    float pn = fmaxf(psh, qg);
    float eo = __expf(psh-pn), en = __expf(qg-pn);
    a = eo*a + en*ag; b = eo*b + en*bg; p = pn;
  }
}

// ------------- WKV pass 3: expand from incoming state, fuse sigmoid(r) -------------
__global__ __launch_bounds__(256) void wkv_out_k(
    const float* __restrict__ kb, const float* __restrict__ vb, const float* __restrict__ rb,
    const float* __restrict__ tfp, const float* __restrict__ tdp,
    const float* __restrict__ prea, const float* __restrict__ preb, const float* __restrict__ prep,
    u16* __restrict__ att_in){
  int ch = blockIdx.x*256 + threadIdx.x;
  int g = blockIdx.y;
  int t0 = g*SEG;
  float tf = tfp[ch], td = tdp[ch];
  size_t so = (size_t)g*Dn + ch;
  float aa = prea[so], bb = preb[so], pp = prep[so];
  float kk[SEG], vv[SEG], rr[SEG];
#pragma unroll
  for(int j=0;j<SEG;j++){
    kk[j]=kb[(size_t)(t0+j)*Dn+ch];
    vv[j]=vb[(size_t)(t0+j)*Dn+ch];
    rr[j]=rb[(size_t)(t0+j)*Dn+ch];
  }
#pragma unroll
  for(int j=0;j<SEG;j++){
    float kt=kk[j], vt=vv[j];
    float ww = tf + kt;
    float p = fmaxf(pp, ww);
    float e1 = __expf(pp-p), e2 = __expf(ww-p);
    float out = __fdividef(e1*aa+e2*vt, e1*bb+e2);
    float sig = __fdividef(1.f, 1.f+__expf(-rr[j]));
    att_in[(size_t)(t0+j)*Dn+ch] = f2b(sig*out);
    float ww2 = pp+td;
    float p2 = fmaxf(ww2,kt);
    e1 = __expf(ww2-p2); e2 = __expf(kt-p2);
    aa = e1*aa+e2*vt; bb = e1*bb+e2; pp = p2;
  }
}

// ------------- bf16 GEMM (R10-proven): 64x64 tile, WAVES-way split-K, dyn LDS -------------
// EPI 0: Cf(+z*strideC) = acc   EPI 2: Cf += acc   EPI 3: Cf += sigmoid(aux)*acc
template<int EPI, int KSTEP, int WAVES>
__global__ __launch_bounds__(WAVES*64) void gemm_k(
    const u16* __restrict__ A, size_t ldA, size_t strideA,
    const u16* __restrict__ Bt, size_t ldB, size_t strideB,
    int K, int N,
    float* __restrict__ Cf, size_t strideC, u16* __restrict__ Cb,
    const float* __restrict__ aux){
  extern __shared__ __align__(16) u16 ldsd[];     // [2 buf][2 op][64*KSTEP]
  constexpr int RPC = 512/KSTEP;
  constexpr int LPR = 64/RPC;
  constexpr int NCH = KSTEP/8;
  constexpr int NQ  = NCH/WAVES;
  constexpr int WKB = 2*KSTEP/WAVES;
  constexpr int NS  = WKB/32;
  const int tid = threadIdx.x;
  const int l = tid & 63, w = tid >> 6;
  const int z = blockIdx.z;
  const int row0 = blockIdx.y*64, col0 = blockIdx.x*64;

  const u16* bA = A  + (size_t)z*strideA + (size_t)row0*ldA;
  const u16* bB = Bt + (size_t)z*strideB + (size_t)col0*ldB;

  int offA[NQ], offB[NQ], ldso[NQ];
#pragma unroll
  for(int q=0;q<NQ;q++){
    int ch = q*WAVES + w;
    int r  = ch*RPC + l/LPR;
    int phys = (l%LPR)*16;
    int kk = ((phys ^ ((r&15)<<4)) >> 1);
    offA[q] = r*(int)ldA + kk;
    offB[q] = r*(int)ldB + kk;
    ldso[q] = ch*512;
  }
  int foff[2][NS];
#pragma unroll
  for(int i=0;i<2;i++){
    int row = i*32 + (l&31);
#pragma unroll
    for(int s=0;s<NS;s++){
      int c = w*WKB + s*32 + ((l>>5)*16);
      foff[i][s] = row*KSTEP + ((c ^ ((row&15)<<4)) >> 1);
    }
  }

  f32x16 acc[2][2];
#pragma unroll
  for(int i=0;i<2;i++)
#pragma unroll
    for(int j=0;j<2;j++)
#pragma unroll
      for(int e=0;e<16;e++) acc[i][j][e] = 0.f;

  u16* ldsA0 = ldsd;
  u16* ldsB0 = ldsd + 64*KSTEP;
  u16* ldsA1 = ldsd + 2*64*KSTEP;
  u16* ldsB1 = ldsd + 3*64*KSTEP;

#define STAGE(LA, LB) do{ \
  _Pragma("unroll") \
  for(int q=0;q<NQ;q++){ \
    __builtin_amdgcn_global_load_lds((ASG const void*)(const void*)(bA + offA[q]), (ASL void*)(void*)((LA) + ldso[q]), 16, 0, 0); \
    __builtin_amdgcn_global_load_lds((ASG const void*)(const void*)(bB + offB[q]), (ASL void*)(void*)((LB) + ldso[q]), 16, 0, 0); \
  } \
  bA += KSTEP; bB += KSTEP; }while(0)

  const int nss = K / KSTEP;
  STAGE(ldsA0, ldsB0);
  __syncthreads();
  int buf = 0;
  for(int ss=0; ss<nss; ss++){
    if(ss+1 < nss){
      if(buf) STAGE(ldsA0, ldsB0); else STAGE(ldsA1, ldsB1);
    }
    const u16* La = buf ? ldsA1 : ldsA0;
    const u16* Lb = buf ? ldsB1 : ldsB0;
#pragma unroll
    for(int s=0;s<NS;s++){
      short8 a0 = *(const short8*)(La + foff[0][s]);
      short8 a1 = *(const short8*)(La + foff[1][s]);
      short8 b0 = *(const short8*)(Lb + foff[0][s]);
      short8 b1 = *(const short8*)(Lb + foff[1][s]);
      acc[0][0] = __builtin_amdgcn_mfma_f32_32x32x16_bf16(a0, b0, acc[0][0], 0, 0, 0);
      acc[0][1] = __builtin_amdgcn_mfma_f32_32x32x16_bf16(a0, b1, acc[0][1], 0, 0, 0);
      acc[1][0] = __builtin_amdgcn_mfma_f32_32x32x16_bf16(a1, b0, acc[1][0], 0, 0, 0);
      acc[1][1] = __builtin_amdgcn_mfma_f32_32x32x16_bf16(a1, b1, acc[1][1], 0, 0, 0);
    }
    __syncthreads();
    buf ^= 1;
  }
#undef STAGE

  float* red = (float*)ldsd;
  if(w > 0){
#pragma unroll
    for(int i=0;i<2;i++)
#pragma unroll
      for(int j=0;j<2;j++)
#pragma unroll
        for(int reg=0;reg<16;reg++){
          int rr_ = (reg&3) + 8*(reg>>2) + 4*(l>>5);
          red[(size_t)(w-1)*4096 + (size_t)(i*32 + rr_)*64 + j*32 + (l&31)] = acc[i][j][reg];
        }
  }
  __syncthreads();
  if(w == 0){
#pragma unroll
    for(int i=0;i<2;i++)
#pragma unroll
      for(int j=0;j<2;j++)
#pragma unroll
        for(int reg=0;reg<16;reg++){
          int rr_ = (reg&3) + 8*(reg>>2) + 4*(l>>5);
          size_t lidx = (size_t)(i*32 + rr_)*64 + j*32 + (l&31);
          float v = acc[i][j][reg];
#pragma unroll
          for(int p=0;p<WAVES-1;p++) v += red[(size_t)p*4096 + lidx];
          int grow = row0 + i*32 + rr_;
          int gcol = col0 + j*32 + (l&31);
          size_t idx = (size_t)grow*N + gcol;
          if constexpr(EPI==0){ Cf[(size_t)z*strideC + idx] = v; }
          else if constexpr(EPI==2){ Cf[idx] += v; }
          else { float s_ = __fdividef(1.f, 1.f+__expf(-aux[idx])); Cf[idx] += s_*v; }
        }
  }
}

// ------------- 128x128-tile GEMM (R12-proven structure, generalized): -------------
// KSTEP=64, 4 waves in 2x2 quadrants (each owns a 64x64 output quadrant, no reduce),
// 64 KB LDS (2 blocks/CU), global_load_lds + 8-slot XOR swizzle.
// EPI 0: Cf[z*strideC + idx] = acc (fp32)   EPI 1: Cb = bf16(relu(acc)^2)
template<int EPI>
__global__ __launch_bounds__(256) void gemm2_k(
    const u16* __restrict__ A, size_t ldA, size_t strideA,
    const u16* __restrict__ Bt, size_t ldB, size_t strideB,
    int K, int N,
    float* __restrict__ Cf, size_t strideC, u16* __restrict__ Cb){
  extern __shared__ __align__(16) u16 ldsd[];   // [2 buf][A 128x64 | B 128x64] = 64 KB
  constexpr int KS = 64;                         // KSTEP elems
  const int tid = threadIdx.x;
  const int l = tid & 63, w = tid >> 6;
  const int wm = (w>>1)*64, wn = (w&1)*64;       // wave quadrant
  const int z = blockIdx.z;
  const int row0 = blockIdx.y*128, col0 = blockIdx.x*128;

  const u16* bA = A  + (size_t)z*strideA + (size_t)row0*ldA;
  const u16* bB = Bt + (size_t)z*strideB + (size_t)col0*ldB;

  // staging: per operand 128 rows x 128 B = 16 chunks of 1 KB; wave w owns chunks q*4+w.
  // chunk ch: row r = ch*8 + (l>>3); phys byte (l&7)*16; src pre-swizzled by ((r&7)<<4).
  int offA[4], offB[4], ldso[4];
#pragma unroll
  for(int q=0;q<4;q++){
    int ch = q*4 + w;
    int r  = ch*8 + (l>>3);
    int kk = ((((l&7)*16) ^ ((l>>3)<<4)) >> 1);
    offA[q] = r*(int)ldA + kk;
    offB[q] = r*(int)ldB + kk;
    ldso[q] = ch*512;                            // u16 elems
  }
  // fragment reads: quadrant-local rows, 4 k-slices of 32 B; swizzle key (row&7)<<4
  int foffA[2][4], foffB[2][4];
#pragma unroll
  for(int i=0;i<2;i++){
    int ar = wm + i*32 + (l&31);
    int br = wn + i*32 + (l&31);
#pragma unroll
    for(int s=0;s<4;s++){
      int c = s*32 + ((l>>5)*16);
      foffA[i][s] = ar*KS + ((c ^ ((ar&7)<<4)) >> 1);
      foffB[i][s] = br*KS + ((c ^ ((br&7)<<4)) >> 1);
    }
  }

  f32x16 acc[2][2];
#pragma unroll
  for(int i=0;i<2;i++)
#pragma unroll
    for(int j=0;j<2;j++)
#pragma unroll
      for(int e=0;e<16;e++) acc[i][j][e] = 0.f;

  u16* ldsA0 = ldsd;                 // 128*64 = 8192 u16 = 16 KB
  u16* ldsB0 = ldsd + 8192;
  u16* ldsA1 = ldsd + 16384;
  u16* ldsB1 = ldsd + 24576;

#define STAGE(LA, LB) do{ \
  _Pragma("unroll") \
  for(int q=0;q<4;q++){ \
    __builtin_amdgcn_global_load_lds((ASG const void*)(const void*)(bA + offA[q]), (ASL void*)(void*)((LA) + ldso[q]), 16, 0, 0); \
    __builtin_amdgcn_global_load_lds((ASG const void*)(const void*)(bB + offB[q]), (ASL void*)(void*)((LB) + ldso[q]), 16, 0, 0); \
  } \
  bA += KS; bB += KS; }while(0)

  const int nss = K / KS;
  STAGE(ldsA0, ldsB0);
  __syncthreads();
  int buf = 0;
#pragma unroll 1
  for(int ss=0; ss<nss; ss++){
    if(ss+1 < nss){
      if(buf) STAGE(ldsA0, ldsB0); else STAGE(ldsA1, ldsB1);
    }
    const u16* La = buf ? ldsA1 : ldsA0;
    const u16* Lb = buf ? ldsB1 : ldsB0;
#pragma unroll
    for(int s=0;s<4;s++){
      short8 a0 = *(const short8*)(La + foffA[0][s]);
      short8 a1 = *(const short8*)(La + foffA[1][s]);
      short8 b0 = *(const short8*)(Lb + foffB[0][s]);
      short8 b1 = *(const short8*)(Lb + foffB[1][s]);
      acc[0][0] = __builtin_amdgcn_mfma_f32_32x32x16_bf16(a0, b0, acc[0][0], 0, 0, 0);
      acc[0][1] = __builtin_amdgcn_mfma_f32_32x32x16_bf16(a0, b1, acc[0][1], 0, 0, 0);
      acc[1][0] = __builtin_amdgcn_mfma_f32_32x32x16_bf16(a1, b0, acc[1][0], 0, 0, 0);
      acc[1][1] = __builtin_amdgcn_mfma_f32_32x32x16_bf16(a1, b1, acc[1][1], 0, 0, 0);
    }
    __syncthreads();
    buf ^= 1;
  }
#undef STAGE

  // epilogue: each wave writes its own quadrant (no reduce)
#pragma unroll
  for(int i=0;i<2;i++){
#pragma unroll
    for(int j=0;j<2;j++){
#pragma unroll
      for(int reg=0;reg<16;reg++){
        int rr_ = (reg&3) + 8*(reg>>2) + 4*(l>>5);
        int grow = row0 + wm + i*32 + rr_;
        int gcol = col0 + wn + j*32 + (l&31);
        float v = acc[i][j][reg];
        size_t idx = (size_t)grow*N + gcol;
        if constexpr(EPI==0){ Cf[(size_t)z*strideC + idx] = v; }
        else { float t_ = v>0.f ? v : 0.f; Cb[idx] = f2b(t_*t_); }
      }
    }
  }
}

// ------------- final LN of last row -------------
__global__ __launch_bounds__(256) void lnout_k(
    const float* __restrict__ x, const float* __restrict__ w, const float* __restrict__ b,
    float* __restrict__ xo){
  int tid = threadIdx.x;
  f4 v = ((const f4*)(x + (size_t)(Tn-1)*Dn))[tid];
  f4 st;
  st.x = v.x+v.y+v.z+v.w;
  st.y = v.x*v.x+v.y*v.y+v.z*v.z+v.w*v.w;
  st.z = 0.f; st.w = 0.f;
  f4 red = blockReduce4(st);
  float mu = red.x*(1.f/Dn);
  float rs = rsqrtf(red.y*(1.f/Dn) - mu*mu + 1e-5f);
  f4 wv = ((const f4*)w)[tid], bv = ((const f4*)b)[tid];
  f4 o;
  o.x = (v.x-mu)*rs*wv.x + bv.x;
  o.y = (v.y-mu)*rs*wv.y + bv.y;
  o.z = (v.z-mu)*rs*wv.z + bv.z;
  o.w = (v.w-mu)*rs*wv.w + bv.w;
  ((f4*)xo)[tid] = o;
}

// ------------- head matvec: logits[V] = head[V,D] @ xo[D] -------------
__global__ __launch_bounds__(256) void head_k(
    const float* __restrict__ head, const float* __restrict__ xo, float* __restrict__ out){
  __shared__ f4 sxo[256];
  int tid = threadIdx.x;
  sxo[tid] = ((const f4*)xo)[tid];
  __syncthreads();
  int w = tid >> 6, lane = tid & 63;
  int row = blockIdx.x*4 + w;
  if(row < Vn){
    const f4* hr = (const f4*)(head + (size_t)row*Dn);
    float s = 0.f;
#pragma unroll
    for(int i=0;i<4;i++){
      f4 h = hr[i*64 + lane];
      f4 xv = sxo[i*64 + lane];
      s += h.x*xv.x + h.y*xv.y + h.z*xv.z + h.w*xv.w;
    }
#pragma unroll
    for(int o=32;o;o>>=1) s += __shfl_xor(s, o);
    if(lane == 0) out[row] = s;
  }
}

extern "C" void kernel_launch(void* const* d_in, const int* in_sizes, int n_in,
                              void* d_out, int out_size, void* d_ws, size_t ws_size,
                              hipStream_t stream) {
  (void)in_sizes; (void)n_in; (void)out_size; (void)ws_size;
  const int*   tokens   = (const int*)  d_in[0];
  const float* emb      = (const float*)d_in[1];
  const float* ln0_w    = (const float*)d_in[2];
  const float* ln0_b    = (const float*)d_in[3];
  const float* ln1_w    = (const float*)d_in[4];
  const float* ln1_b    = (const float*)d_in[5];
  const float* ln2_w    = (const float*)d_in[6];
  const float* ln2_b    = (const float*)d_in[7];
  const float* tmk      = (const float*)d_in[8];
  const float* tmv      = (const float*)d_in[9];
  const float* tmr      = (const float*)d_in[10];
  const float* tmk_ffn  = (const float*)d_in[11];
  const float* tmr_ffn  = (const float*)d_in[12];
  const float* tfirst   = (const float*)d_in[13];
  const float* tdecay   = (const float*)d_in[14];
  const float* att_kw   = (const float*)d_in[15];
  const float* att_vw   = (const float*)d_in[16];
  const float* att_rw   = (const float*)d_in[17];
  const float* att_ow   = (const float*)d_in[18];
  const float* ffn_kw   = (const float*)d_in[19];
  const float* ffn_vw   = (const float*)d_in[20];
  const float* ffn_rw   = (const float*)d_in[21];
  const float* lnoutw   = (const float*)d_in[22];
  const float* lnoutb   = (const float*)d_in[23];
  const float* headw    = (const float*)d_in[24];
  float* logits = (float*)d_out;

  char* wsb = (char*)d_ws;
  size_t off = 0;
  auto carve = [&](size_t bytes)->void*{
    void* p = wsb + off;
    off += (bytes + 255) & ~(size_t)255;
    return p;
  };
  float* x      = (float*)carve((size_t)TDn*4);
  u16*   xkvr   = (u16*)  carve((size_t)3*TDn*2);
  float* kvr    = (float*)carve((size_t)3*TDn*4);
  u16*   att_in = (u16*)  carve((size_t)TDn*2);
  u16*   xkr    = (u16*)  carve((size_t)2*TDn*2);
  u16*   kf     = (u16*)  carve((size_t)Tn*F4n*2);
  float* rf     = (float*)carve((size_t)TDn*4);
  float* xo     = (float*)carve((size_t)Dn*4);
  u16*   wbt    = (u16*)  carve((size_t)13*MEG*2);
  float* sega   = (float*)carve((size_t)NSEG*Dn*4);
  float* segb   = (float*)carve((size_t)NSEG*Dn*4);
  float* segp   = (float*)carve((size_t)NSEG*Dn*4);
  float* prea   = (float*)carve((size_t)NSEG*Dn*4);
  float* preb   = (float*)carve((size_t)NSEG*Dn*4);
  float* prep   = (float*)carve((size_t)NSEG*Dn*4);

  embed_ln0_k<<<Tn, 256, 0, stream>>>(tokens, emb, ln0_w, ln0_b, x);

  for(int i=0;i<Ln;i++){
    size_t dd = (size_t)i*Dn*Dn;
    ConvArgs ca;
    ca.s0 = att_kw+dd; ca.s1 = att_vw+dd; ca.s2 = att_rw+dd; ca.s3 = att_ow+dd;
    ca.skw = ffn_kw+(size_t)i*Dn*F4n; ca.svw = ffn_vw+(size_t)i*F4n*Dn; ca.srw = ffn_rw+dd;
    ca.dst = wbt;
    conv_k<<<3328, 256, 0, stream>>>(ca);

    // --- time mix ---
    ln_mix_att_k<<<Tn, 256, 0, stream>>>(x, ln1_w+i*Dn, ln1_b+i*Dn,
                                         tmk+i*Dn, tmv+i*Dn, tmr+i*Dn, xkvr);
    gemm2_k<0><<<dim3(8,8,3), 256, 65536, stream>>>(
        xkvr, Dn, (size_t)TDn, wbt, Dn, (size_t)MEG, Dn, Dn,
        kvr, (size_t)TDn, nullptr);
    wkv_seg_k<<<dim3(4,NSEG), 256, 0, stream>>>(kvr, kvr+TDn, tdecay+i*Dn, sega, segb, segp);
    wkv_scan_k<<<4, 256, 0, stream>>>(sega, segb, segp, tdecay+i*Dn, prea, preb, prep);
    wkv_out_k<<<dim3(4,NSEG), 256, 0, stream>>>(kvr, kvr+TDn, kvr+2*TDn,
                                                tfirst+i*Dn, tdecay+i*Dn,
                                                prea, preb, prep, att_in);
    gemm_k<2,256,4><<<dim3(16,16,1), 256, 131072, stream>>>(
        att_in, Dn, 0, wbt+(size_t)3*MEG, Dn, 0, Dn, Dn,
        x, 0, nullptr, nullptr);
    // --- channel mix ---
    ln_mix_ffn_k<<<Tn, 256, 0, stream>>>(x, ln2_w+i*Dn, ln2_b+i*Dn,
                                         tmk_ffn+i*Dn, tmr_ffn+i*Dn, xkr);
    gemm2_k<1><<<dim3(32,8,1), 256, 65536, stream>>>(
        xkr, Dn, 0, wbt+(size_t)4*MEG, Dn, 0, Dn, F4n,
        nullptr, 0, kf);
    gemm_k<0,256,4><<<dim3(16,16,1), 256, 131072, stream>>>(
        xkr+TDn, Dn, 0, wbt+(size_t)12*MEG, Dn, 0, Dn, Dn,
        rf, 0, nullptr, nullptr);
    gemm_k<3,256,4><<<dim3(16,16,1), 256, 131072, stream>>>(
        kf, F4n, 0, wbt+(size_t)8*MEG, F4n, 0, F4n, Dn,
        x, 0, nullptr, rf);
  }

  lnout_k<<<1, 256, 0, stream>>>(x, lnoutw, lnoutb, xo);
  head_k<<<(Vn+3)/4, 256, 0, stream>>>(headw, xo, logits);
}

// Round 14
// 1696.298 us; speedup vs baseline: 1.2171x; 1.0362x over previous
//
#include <hip/hip_runtime.h>

#define Tn 1024
#define Dn 1024
#define Ln 12
#define F4n 4096
#define Vn 50277
#define TDn (Tn*Dn)
#define MEG 1048576
#define SEG 16
#define NSEG 64

typedef __attribute__((ext_vector_type(4))) float f4;
typedef __attribute__((ext_vector_type(16))) float f32x16;
typedef __attribute__((ext_vector_type(8))) short short8;
typedef unsigned short u16;
typedef unsigned int u32;
typedef __attribute__((ext_vector_type(4))) u16 us4;

#define ASG __attribute__((address_space(1)))
#define ASL __attribute__((address_space(3)))

__device__ __forceinline__ u16 f2b(float x){   // f32 -> bf16 RNE
  u32 u = __float_as_uint(x);
  return (u16)((u + 0x7fffu + ((u >> 16) & 1u)) >> 16);
}

// reduce 4 independent sums across a 256-thread block
__device__ __forceinline__ f4 blockReduce4(f4 v){
  __shared__ f4 s[4];
  int lane = threadIdx.x & 63, w = threadIdx.x >> 6;
#pragma unroll
  for(int o = 32; o; o >>= 1){
    v.x += __shfl_xor(v.x, o);
    v.y += __shfl_xor(v.y, o);
    v.z += __shfl_xor(v.z, o);
    v.w += __shfl_xor(v.w, o);
  }
  if(lane == 0) s[w] = v;
  __syncthreads();
  return s[0] + s[1] + s[2] + s[3];
}

// ---------------- per-layer weight convert + transpose: fp32 [K][N] -> bf16 [N][K] ----------------
struct ConvArgs {
  const float* s0; const float* s1; const float* s2; const float* s3;  // att k,v,r,o [1024][1024]
  const float* skw;  // [1024][4096]
  const float* svw;  // [4096][1024]
  const float* srw;  // [1024][1024]
  u16* dst;          // 13M elems: k@0 v@1M r@2M o@3M fk@4M fv@8M fr@12M
};
__global__ __launch_bounds__(256) void conv_k(ConvArgs a){
  __shared__ __align__(16) u16 t[64][68];
  int b = blockIdx.x, tid = threadIdx.x;
  const float* src; u16* dst; int K, N, tk, tn;
  if(b < 1024){
    int m = b >> 8, bt = b & 255;
    src = (m==0)?a.s0:((m==1)?a.s1:((m==2)?a.s2:a.s3));
    dst = a.dst + (size_t)m*MEG; K=1024; N=1024; tk=bt>>4; tn=bt&15;
  } else if(b < 2048){
    int bt = b-1024; src=a.skw; dst=a.dst+(size_t)4*MEG; K=1024; N=4096; tk=bt>>6; tn=bt&63;
  } else if(b < 3072){
    int bt = b-2048; src=a.svw; dst=a.dst+(size_t)8*MEG; K=4096; N=1024; tk=bt>>4; tn=bt&15;
  } else {
    int bt = b-3072; src=a.srw; dst=a.dst+(size_t)12*MEG; K=1024; N=1024; tk=bt>>4; tn=bt&15;
  }
  int rr0 = tid >> 4, c4 = (tid & 15)*4;
#pragma unroll
  for(int p=0;p<4;p++){
    int r = p*16 + rr0;
    f4 v = *(const f4*)(src + (size_t)(tk*64+r)*N + tn*64 + c4);
    us4 h; h[0]=f2b(v.x); h[1]=f2b(v.y); h[2]=f2b(v.z); h[3]=f2b(v.w);
    *(us4*)&t[r][c4] = h;
  }
  __syncthreads();
  int q = tid & 3, n = tid >> 2;
  int k0 = q*16;
  union { short8 v; u16 h[8]; } o0, o1;
#pragma unroll
  for(int j=0;j<8;j++){ o0.h[j]=t[k0+j][n]; o1.h[j]=t[k0+8+j][n]; }
  u16* dp = dst + (size_t)(tn*64+n)*K + tk*64 + k0;
  *(short8*)dp       = o0.v;
  *(short8*)(dp + 8) = o1.v;
}

// ---------------- embedding + ln0 ----------------
__global__ __launch_bounds__(256) void embed_ln0_k(
    const int* __restrict__ tok, const float* __restrict__ emb,
    const float* __restrict__ w, const float* __restrict__ b,
    float* __restrict__ x){
  int t = blockIdx.x, tid = threadIdx.x;
  const f4* src = (const f4*)(emb + (size_t)tok[t] * Dn);
  f4 v = src[tid];
  f4 st;
  st.x = v.x+v.y+v.z+v.w;
  st.y = v.x*v.x+v.y*v.y+v.z*v.z+v.w*v.w;
  st.z = 0.f; st.w = 0.f;
  f4 red = blockReduce4(st);
  float mu = red.x * (1.0f/Dn);
  float rs = rsqrtf(red.y * (1.0f/Dn) - mu*mu + 1e-5f);
  f4 wv = ((const f4*)w)[tid], bv = ((const f4*)b)[tid];
  f4 o;
  o.x = (v.x-mu)*rs*wv.x + bv.x;
  o.y = (v.y-mu)*rs*wv.y + bv.y;
  o.z = (v.z-mu)*rs*wv.z + bv.z;
  o.w = (v.w-mu)*rs*wv.w + bv.w;
  ((f4*)(x + (size_t)t*Dn))[tid] = o;
}

// ------------- LN + token-shift + mix (attention: k,v,r) -------------
__global__ __launch_bounds__(256) void ln_mix_att_k(
    const float* __restrict__ x,
    const float* __restrict__ lw, const float* __restrict__ lb,
    const float* __restrict__ tk, const float* __restrict__ tv, const float* __restrict__ tr,
    u16* __restrict__ xkvr){
  int t = blockIdx.x, tid = threadIdx.x;
  f4 cur = ((const f4*)(x + (size_t)t*Dn))[tid];
  f4 prv; prv.x=0.f; prv.y=0.f; prv.z=0.f; prv.w=0.f;
  if(t > 0) prv = ((const f4*)(x + (size_t)(t-1)*Dn))[tid];
  f4 st;
  st.x = cur.x+cur.y+cur.z+cur.w;
  st.y = cur.x*cur.x+cur.y*cur.y+cur.z*cur.z+cur.w*cur.w;
  st.z = prv.x+prv.y+prv.z+prv.w;
  st.w = prv.x*prv.x+prv.y*prv.y+prv.z*prv.z+prv.w*prv.w;
  f4 red = blockReduce4(st);
  float muc = red.x*(1.f/Dn), rsc = rsqrtf(red.y*(1.f/Dn)-muc*muc+1e-5f);
  float mup = red.z*(1.f/Dn), rsp = rsqrtf(red.w*(1.f/Dn)-mup*mup+1e-5f);
  f4 wv=((const f4*)lw)[tid], bv=((const f4*)lb)[tid];
  f4 kv=((const f4*)tk)[tid], vv=((const f4*)tv)[tid], rv=((const f4*)tr)[tid];
  us4 ok, ov, orr;
  float xn, xp;
#define MIX3(j, cj, pj, wj, bj, kj, vj, rj) \
  xn = (cj - muc)*rsc*wj + bj; \
  xp = (t>0) ? ((pj - mup)*rsp*wj + bj) : 0.f; \
  ok[j]  = f2b(xn*kj + xp*(1.f-kj)); \
  ov[j]  = f2b(xn*vj + xp*(1.f-vj)); \
  orr[j] = f2b(xn*rj + xp*(1.f-rj));
  MIX3(0, cur.x, prv.x, wv.x, bv.x, kv.x, vv.x, rv.x)
  MIX3(1, cur.y, prv.y, wv.y, bv.y, kv.y, vv.y, rv.y)
  MIX3(2, cur.z, prv.z, wv.z, bv.z, kv.z, vv.z, rv.z)
  MIX3(3, cur.w, prv.w, wv.w, bv.w, kv.w, vv.w, rv.w)
#undef MIX3
  size_t o0 = (size_t)t*Dn + tid*4;
  *(us4*)(xkvr + o0)         = ok;
  *(us4*)(xkvr + TDn + o0)   = ov;
  *(us4*)(xkvr + 2*TDn + o0) = orr;
}

// ------------- LN + token-shift + mix (ffn: k,r) -------------
__global__ __launch_bounds__(256) void ln_mix_ffn_k(
    const float* __restrict__ x,
    const float* __restrict__ lw, const float* __restrict__ lb,
    const float* __restrict__ tk, const float* __restrict__ tr,
    u16* __restrict__ xkr){
  int t = blockIdx.x, tid = threadIdx.x;
  f4 cur = ((const f4*)(x + (size_t)t*Dn))[tid];
  f4 prv; prv.x=0.f; prv.y=0.f; prv.z=0.f; prv.w=0.f;
  if(t > 0) prv = ((const f4*)(x + (size_t)(t-1)*Dn))[tid];
  f4 st;
  st.x = cur.x+cur.y+cur.z+cur.w;
  st.y = cur.x*cur.x+cur.y*cur.y+cur.z*cur.z+cur.w*cur.w;
  st.z = prv.x+prv.y+prv.z+prv.w;
  st.w = prv.x*prv.x+prv.y*prv.y+prv.z*prv.z+prv.w*prv.w;
  f4 red = blockReduce4(st);
  float muc = red.x*(1.f/Dn), rsc = rsqrtf(red.y*(1.f/Dn)-muc*muc+1e-5f);
  float mup = red.z*(1.f/Dn), rsp = rsqrtf(red.w*(1.f/Dn)-mup*mup+1e-5f);
  f4 wv=((const f4*)lw)[tid], bv=((const f4*)lb)[tid];
  f4 kv=((const f4*)tk)[tid], rv=((const f4*)tr)[tid];
  us4 ok, orr;
  float xn, xp;
#define MIX2(j, cj, pj, wj, bj, kj, rj) \
  xn = (cj - muc)*rsc*wj + bj; \
  xp = (t>0) ? ((pj - mup)*rsp*wj + bj) : 0.f; \
  ok[j]  = f2b(xn*kj + xp*(1.f-kj)); \
  orr[j] = f2b(xn*rj + xp*(1.f-rj));
  MIX2(0, cur.x, prv.x, wv.x, bv.x, kv.x, rv.x)
  MIX2(1, cur.y, prv.y, wv.y, bv.y, kv.y, rv.y)
  MIX2(2, cur.z, prv.z, wv.z, bv.z, kv.z, rv.z)
  MIX2(3, cur.w, prv.w, wv.w, bv.w, kv.w, rv.w)
#undef MIX2
  size_t o0 = (size_t)t*Dn + tid*4;
  *(us4*)(xkr + o0)       = ok;
  *(us4*)(xkr + TDn + o0) = orr;
}

// ------------- WKV chunked scan, pass 1 -------------
__global__ __launch_bounds__(256) void wkv_seg_k(
    const float* __restrict__ kb, const float* __restrict__ vb,
    const float* __restrict__ tdp,
    float* __restrict__ sega, float* __restrict__ segb, float* __restrict__ segp){
  int ch = blockIdx.x*256 + threadIdx.x;
  int g = blockIdx.y;
  int t0 = g*SEG;
  float td = tdp[ch];
  float kk[SEG], vv[SEG];
#pragma unroll
  for(int j=0;j<SEG;j++){
    kk[j] = kb[(size_t)(t0+j)*Dn + ch];
    vv[j] = vb[(size_t)(t0+j)*Dn + ch];
  }
  float aa=0.f, bb=0.f, pp=-1e30f;
#pragma unroll
  for(int j=0;j<SEG;j++){
    float ww2 = pp + td;
    float p2 = fmaxf(ww2, kk[j]);
    float e1 = __expf(ww2-p2), e2 = __expf(kk[j]-p2);
    aa = e1*aa + e2*vv[j]; bb = e1*bb + e2; pp = p2;
  }
  size_t o = (size_t)g*Dn + ch;
  sega[o] = aa; segb[o] = bb; segp[o] = pp;
}

// ------------- WKV pass 2: serial compose over segments -------------
__global__ __launch_bounds__(256) void wkv_scan_k(
    const float* __restrict__ sega, const float* __restrict__ segb, const float* __restrict__ segp,
    const float* __restrict__ tdp,
    float* __restrict__ prea, float* __restrict__ preb, float* __restrict__ prep){
  int ch = blockIdx.x*256 + threadIdx.x;
  float Std = tdp[ch] * (float)SEG;
  float a=0.f, b=0.f, p=-1e30f;
  for(int g=0; g<NSEG; g++){
    size_t o = (size_t)g*Dn + ch;
    prea[o]=a; preb[o]=b; prep[o]=p;
    float ag=sega[o], bg=segb[o], qg=segp[o];
    float psh = p + Std;
    float pn = fmaxf(psh, qg);
    float eo = __expf(psh-pn), en = __expf(qg-pn);
    a = eo*a + en*ag; b = eo*b + en*bg; p = pn;
  }
}

// ------------- WKV pass 3: expand from incoming state, fuse sigmoid(r) -------------
__global__ __launch_bounds__(256) void wkv_out_k(
    const float* __restrict__ kb, const float* __restrict__ vb, const float* __restrict__ rb,
    const float* __restrict__ tfp, const float* __restrict__ tdp,
    const float* __restrict__ prea, const float* __restrict__ preb, const float* __restrict__ prep,
    u16* __restrict__ att_in){
  int ch = blockIdx.x*256 + threadIdx.x;
  int g = blockIdx.y;
  int t0 = g*SEG;
  float tf = tfp[ch], td = tdp[ch];
  size_t so = (size_t)g*Dn + ch;
  float aa = prea[so], bb = preb[so], pp = prep[so];
  float kk[SEG], vv[SEG], rr[SEG];
#pragma unroll
  for(int j=0;j<SEG;j++){
    kk[j]=kb[(size_t)(t0+j)*Dn+ch];
    vv[j]=vb[(size_t)(t0+j)*Dn+ch];
    rr[j]=rb[(size_t)(t0+j)*Dn+ch];
  }
#pragma unroll
  for(int j=0;j<SEG;j++){
    float kt=kk[j], vt=vv[j];
    float ww = tf + kt;
    float p = fmaxf(pp, ww);
    float e1 = __expf(pp-p), e2 = __expf(ww-p);
    float out = __fdividef(e1*aa+e2*vt, e1*bb+e2);
    float sig = __fdividef(1.f, 1.f+__expf(-rr[j]));
    att_in[(size_t)(t0+j)*Dn+ch] = f2b(sig*out);
    float ww2 = pp+td;
    float p2 = fmaxf(ww2,kt);
    e1 = __expf(ww2-p2); e2 = __expf(kt-p2);
    aa = e1*aa+e2*vt; bb = e1*bb+e2; pp = p2;
  }
}

// ------------- bf16 GEMM (R10-proven): 64x64 tile, WAVES-way split-K, dyn LDS -------------
// EPI 0: Cf(+z*strideC) = acc   EPI 2: Cf += acc   EPI 3: Cf += sigmoid(aux)*acc
template<int EPI, int KSTEP, int WAVES>
__global__ __launch_bounds__(WAVES*64) void gemm_k(
    const u16* __restrict__ A, size_t ldA, size_t strideA,
    const u16* __restrict__ Bt, size_t ldB, size_t strideB,
    int K, int N,
    float* __restrict__ Cf, size_t strideC, u16* __restrict__ Cb,
    const float* __restrict__ aux){
  extern __shared__ __align__(16) u16 ldsd[];     // [2 buf][2 op][64*KSTEP]
  constexpr int RPC = 512/KSTEP;
  constexpr int LPR = 64/RPC;
  constexpr int NCH = KSTEP/8;
  constexpr int NQ  = NCH/WAVES;
  constexpr int WKB = 2*KSTEP/WAVES;
  constexpr int NS  = WKB/32;
  const int tid = threadIdx.x;
  const int l = tid & 63, w = tid >> 6;
  const int z = blockIdx.z;
  const int row0 = blockIdx.y*64, col0 = blockIdx.x*64;

  const u16* bA = A  + (size_t)z*strideA + (size_t)row0*ldA;
  const u16* bB = Bt + (size_t)z*strideB + (size_t)col0*ldB;

  int offA[NQ], offB[NQ], ldso[NQ];
#pragma unroll
  for(int q=0;q<NQ;q++){
    int ch = q*WAVES + w;
    int r  = ch*RPC + l/LPR;
    int phys = (l%LPR)*16;
    int kk = ((phys ^ ((r&15)<<4)) >> 1);
    offA[q] = r*(int)ldA + kk;
    offB[q] = r*(int)ldB + kk;
    ldso[q] = ch*512;
  }
  int foff[2][NS];
#pragma unroll
  for(int i=0;i<2;i++){
    int row = i*32 + (l&31);
#pragma unroll
    for(int s=0;s<NS;s++){
      int c = w*WKB + s*32 + ((l>>5)*16);
      foff[i][s] = row*KSTEP + ((c ^ ((row&15)<<4)) >> 1);
    }
  }

  f32x16 acc[2][2];
#pragma unroll
  for(int i=0;i<2;i++)
#pragma unroll
    for(int j=0;j<2;j++)
#pragma unroll
      for(int e=0;e<16;e++) acc[i][j][e] = 0.f;

  u16* ldsA0 = ldsd;
  u16* ldsB0 = ldsd + 64*KSTEP;
  u16* ldsA1 = ldsd + 2*64*KSTEP;
  u16* ldsB1 = ldsd + 3*64*KSTEP;

#define STAGE(LA, LB) do{ \
  _Pragma("unroll") \
  for(int q=0;q<NQ;q++){ \
    __builtin_amdgcn_global_load_lds((ASG const void*)(const void*)(bA + offA[q]), (ASL void*)(void*)((LA) + ldso[q]), 16, 0, 0); \
    __builtin_amdgcn_global_load_lds((ASG const void*)(const void*)(bB + offB[q]), (ASL void*)(void*)((LB) + ldso[q]), 16, 0, 0); \
  } \
  bA += KSTEP; bB += KSTEP; }while(0)

  const int nss = K / KSTEP;
  STAGE(ldsA0, ldsB0);
  __syncthreads();
  int buf = 0;
  for(int ss=0; ss<nss; ss++){
    if(ss+1 < nss){
      if(buf) STAGE(ldsA0, ldsB0); else STAGE(ldsA1, ldsB1);
    }
    const u16* La = buf ? ldsA1 : ldsA0;
    const u16* Lb = buf ? ldsB1 : ldsB0;
#pragma unroll
    for(int s=0;s<NS;s++){
      short8 a0 = *(const short8*)(La + foff[0][s]);
      short8 a1 = *(const short8*)(La + foff[1][s]);
      short8 b0 = *(const short8*)(Lb + foff[0][s]);
      short8 b1 = *(const short8*)(Lb + foff[1][s]);
      acc[0][0] = __builtin_amdgcn_mfma_f32_32x32x16_bf16(a0, b0, acc[0][0], 0, 0, 0);
      acc[0][1] = __builtin_amdgcn_mfma_f32_32x32x16_bf16(a0, b1, acc[0][1], 0, 0, 0);
      acc[1][0] = __builtin_amdgcn_mfma_f32_32x32x16_bf16(a1, b0, acc[1][0], 0, 0, 0);
      acc[1][1] = __builtin_amdgcn_mfma_f32_32x32x16_bf16(a1, b1, acc[1][1], 0, 0, 0);
    }
    __syncthreads();
    buf ^= 1;
  }
#undef STAGE

  float* red = (float*)ldsd;
  if(w > 0){
#pragma unroll
    for(int i=0;i<2;i++)
#pragma unroll
      for(int j=0;j<2;j++)
#pragma unroll
        for(int reg=0;reg<16;reg++){
          int rr_ = (reg&3) + 8*(reg>>2) + 4*(l>>5);
          red[(size_t)(w-1)*4096 + (size_t)(i*32 + rr_)*64 + j*32 + (l&31)] = acc[i][j][reg];
        }
  }
  __syncthreads();
  if(w == 0){
#pragma unroll
    for(int i=0;i<2;i++)
#pragma unroll
      for(int j=0;j<2;j++)
#pragma unroll
        for(int reg=0;reg<16;reg++){
          int rr_ = (reg&3) + 8*(reg>>2) + 4*(l>>5);
          size_t lidx = (size_t)(i*32 + rr_)*64 + j*32 + (l&31);
          float v = acc[i][j][reg];
#pragma unroll
          for(int p=0;p<WAVES-1;p++) v += red[(size_t)p*4096 + lidx];
          int grow = row0 + i*32 + rr_;
          int gcol = col0 + j*32 + (l&31);
          size_t idx = (size_t)grow*N + gcol;
          if constexpr(EPI==0){ Cf[(size_t)z*strideC + idx] = v; }
          else if constexpr(EPI==2){ Cf[idx] += v; }
          else { float s_ = __fdividef(1.f, 1.f+__expf(-aux[idx])); Cf[idx] += s_*v; }
        }
  }
}

// ------------- 128x128-tile GEMM (R12/R13-proven): KSTEP=64, 4 waves in 2x2 quadrants, -------------
// no reduce, 64 KB LDS, global_load_lds + 8-slot XOR swizzle.
// EPI 0: Cf[z*strideC + idx] = acc (fp32)   EPI 1: Cb = bf16(relu(acc)^2)
template<int EPI>
__global__ __launch_bounds__(256) void gemm2_k(
    const u16* __restrict__ A, size_t ldA, size_t strideA,
    const u16* __restrict__ Bt, size_t ldB, size_t strideB,
    int K, int N,
    float* __restrict__ Cf, size_t strideC, u16* __restrict__ Cb){
  extern __shared__ __align__(16) u16 ldsd[];   // [2 buf][A 128x64 | B 128x64] = 64 KB
  constexpr int KS = 64;
  const int tid = threadIdx.x;
  const int l = tid & 63, w = tid >> 6;
  const int wm = (w>>1)*64, wn = (w&1)*64;
  const int z = blockIdx.z;
  const int row0 = blockIdx.y*128, col0 = blockIdx.x*128;

  const u16* bA = A  + (size_t)z*strideA + (size_t)row0*ldA;
  const u16* bB = Bt + (size_t)z*strideB + (size_t)col0*ldB;

  int offA[4], offB[4], ldso[4];
#pragma unroll
  for(int q=0;q<4;q++){
    int ch = q*4 + w;
    int r  = ch*8 + (l>>3);
    int kk = ((((l&7)*16) ^ ((l>>3)<<4)) >> 1);
    offA[q] = r*(int)ldA + kk;
    offB[q] = r*(int)ldB + kk;
    ldso[q] = ch*512;
  }
  int foffA[2][4], foffB[2][4];
#pragma unroll
  for(int i=0;i<2;i++){
    int ar = wm + i*32 + (l&31);
    int br = wn + i*32 + (l&31);
#pragma unroll
    for(int s=0;s<4;s++){
      int c = s*32 + ((l>>5)*16);
      foffA[i][s] = ar*KS + ((c ^ ((ar&7)<<4)) >> 1);
      foffB[i][s] = br*KS + ((c ^ ((br&7)<<4)) >> 1);
    }
  }

  f32x16 acc[2][2];
#pragma unroll
  for(int i=0;i<2;i++)
#pragma unroll
    for(int j=0;j<2;j++)
#pragma unroll
      for(int e=0;e<16;e++) acc[i][j][e] = 0.f;

  u16* ldsA0 = ldsd;
  u16* ldsB0 = ldsd + 8192;
  u16* ldsA1 = ldsd + 16384;
  u16* ldsB1 = ldsd + 24576;

#define STAGE(LA, LB) do{ \
  _Pragma("unroll") \
  for(int q=0;q<4;q++){ \
    __builtin_amdgcn_global_load_lds((ASG const void*)(const void*)(bA + offA[q]), (ASL void*)(void*)((LA) + ldso[q]), 16, 0, 0); \
    __builtin_amdgcn_global_load_lds((ASG const void*)(const void*)(bB + offB[q]), (ASL void*)(void*)((LB) + ldso[q]), 16, 0, 0); \
  } \
  bA += KS; bB += KS; }while(0)

  const int nss = K / KS;
  STAGE(ldsA0, ldsB0);
  __syncthreads();
  int buf = 0;
#pragma unroll 1
  for(int ss=0; ss<nss; ss++){
    if(ss+1 < nss){
      if(buf) STAGE(ldsA0, ldsB0); else STAGE(ldsA1, ldsB1);
    }
    const u16* La = buf ? ldsA1 : ldsA0;
    const u16* Lb = buf ? ldsB1 : ldsB0;
#pragma unroll
    for(int s=0;s<4;s++){
      short8 a0 = *(const short8*)(La + foffA[0][s]);
      short8 a1 = *(const short8*)(La + foffA[1][s]);
      short8 b0 = *(const short8*)(Lb + foffB[0][s]);
      short8 b1 = *(const short8*)(Lb + foffB[1][s]);
      acc[0][0] = __builtin_amdgcn_mfma_f32_32x32x16_bf16(a0, b0, acc[0][0], 0, 0, 0);
      acc[0][1] = __builtin_amdgcn_mfma_f32_32x32x16_bf16(a0, b1, acc[0][1], 0, 0, 0);
      acc[1][0] = __builtin_amdgcn_mfma_f32_32x32x16_bf16(a1, b0, acc[1][0], 0, 0, 0);
      acc[1][1] = __builtin_amdgcn_mfma_f32_32x32x16_bf16(a1, b1, acc[1][1], 0, 0, 0);
    }
    __syncthreads();
    buf ^= 1;
  }
#undef STAGE

#pragma unroll
  for(int i=0;i<2;i++){
#pragma unroll
    for(int j=0;j<2;j++){
#pragma unroll
      for(int reg=0;reg<16;reg++){
        int rr_ = (reg&3) + 8*(reg>>2) + 4*(l>>5);
        int grow = row0 + wm + i*32 + rr_;
        int gcol = col0 + wn + j*32 + (l&31);
        float v = acc[i][j][reg];
        size_t idx = (size_t)grow*N + gcol;
        if constexpr(EPI==0){ Cf[(size_t)z*strideC + idx] = v; }
        else { float t_ = v>0.f ? v : 0.f; Cb[idx] = f2b(t_*t_); }
      }
    }
  }
}

// ------------- merged FFN-k + FFN-r at 128x128 geometry: grid (40,8) -------------
// bx<32: fk tile (N=4096, relu^2 -> kf bf16) — interior identical to gemm2_k<1>.
// bx>=32: fr tile (N=1024, fp32 -> rf). Both K=1024, ldA=ldB=1024.
__global__ __launch_bounds__(256) void gemm2_fkr_k(
    const u16* __restrict__ xkr, const u16* __restrict__ wfk, const u16* __restrict__ wfr,
    u16* __restrict__ kf, float* __restrict__ rf){
  extern __shared__ __align__(16) u16 ldsd[];
  constexpr int KS = 64;
  const int tid = threadIdx.x;
  const int l = tid & 63, w = tid >> 6;
  const int wm = (w>>1)*64, wn = (w&1)*64;
  const bool isfk = blockIdx.x < 32;
  const int N = isfk ? F4n : Dn;
  const int col0 = (isfk ? blockIdx.x : blockIdx.x-32)*128;
  const int row0 = blockIdx.y*128;

  const u16* bA = (isfk ? xkr : xkr + TDn) + (size_t)row0*Dn;
  const u16* bB = (isfk ? wfk : wfr) + (size_t)col0*Dn;

  int offA[4], offB[4], ldso[4];
#pragma unroll
  for(int q=0;q<4;q++){
    int ch = q*4 + w;
    int r  = ch*8 + (l>>3);
    int kk = ((((l&7)*16) ^ ((l>>3)<<4)) >> 1);
    offA[q] = r*Dn + kk;
    offB[q] = r*Dn + kk;
    ldso[q] = ch*512;
  }
  int foffA[2][4], foffB[2][4];
#pragma unroll
  for(int i=0;i<2;i++){
    int ar = wm + i*32 + (l&31);
    int br = wn + i*32 + (l&31);
#pragma unroll
    for(int s=0;s<4;s++){
      int c = s*32 + ((l>>5)*16);
      foffA[i][s] = ar*KS + ((c ^ ((ar&7)<<4)) >> 1);
      foffB[i][s] = br*KS + ((c ^ ((br&7)<<4)) >> 1);
    }
  }

  f32x16 acc[2][2];
#pragma unroll
  for(int i=0;i<2;i++)
#pragma unroll
    for(int j=0;j<2;j++)
#pragma unroll
      for(int e=0;e<16;e++) acc[i][j][e] = 0.f;

  u16* ldsA0 = ldsd;
  u16* ldsB0 = ldsd + 8192;
  u16* ldsA1 = ldsd + 16384;
  u16* ldsB1 = ldsd + 24576;

#define STAGE(LA, LB) do{ \
  _Pragma("unroll") \
  for(int q=0;q<4;q++){ \
    __builtin_amdgcn_global_load_lds((ASG const void*)(const void*)(bA + offA[q]), (ASL void*)(void*)((LA) + ldso[q]), 16, 0, 0); \
    __builtin_amdgcn_global_load_lds((ASG const void*)(const void*)(bB + offB[q]), (ASL void*)(void*)((LB) + ldso[q]), 16, 0, 0); \
  } \
  bA += KS; bB += KS; }while(0)

  STAGE(ldsA0, ldsB0);
  __syncthreads();
  int buf = 0;
#pragma unroll 1
  for(int ss=0; ss<16; ss++){     // K=1024/64
    if(ss+1 < 16){
      if(buf) STAGE(ldsA0, ldsB0); else STAGE(ldsA1, ldsB1);
    }
    const u16* La = buf ? ldsA1 : ldsA0;
    const u16* Lb = buf ? ldsB1 : ldsB0;
#pragma unroll
    for(int s=0;s<4;s++){
      short8 a0 = *(const short8*)(La + foffA[0][s]);
      short8 a1 = *(const short8*)(La + foffA[1][s]);
      short8 b0 = *(const short8*)(Lb + foffB[0][s]);
      short8 b1 = *(const short8*)(Lb + foffB[1][s]);
      acc[0][0] = __builtin_amdgcn_mfma_f32_32x32x16_bf16(a0, b0, acc[0][0], 0, 0, 0);
      acc[0][1] = __builtin_amdgcn_mfma_f32_32x32x16_bf16(a0, b1, acc[0][1], 0, 0, 0);
      acc[1][0] = __builtin_amdgcn_mfma_f32_32x32x16_bf16(a1, b0, acc[1][0], 0, 0, 0);
      acc[1][1] = __builtin_amdgcn_mfma_f32_32x32x16_bf16(a1, b1, acc[1][1], 0, 0, 0);
    }
    __syncthreads();
    buf ^= 1;
  }
#undef STAGE

#pragma unroll
  for(int i=0;i<2;i++){
#pragma unroll
    for(int j=0;j<2;j++){
#pragma unroll
      for(int reg=0;reg<16;reg++){
        int rr_ = (reg&3) + 8*(reg>>2) + 4*(l>>5);
        int grow = row0 + wm + i*32 + rr_;
        int gcol = col0 + wn + j*32 + (l&31);
        float v = acc[i][j][reg];
        size_t idx = (size_t)grow*N + gcol;
        if(isfk){ float t_ = v>0.f ? v : 0.f; kf[idx] = f2b(t_*t_); }
        else rf[idx] = v;
      }
    }
  }
}

// ------------- final LN of last row -------------
__global__ __launch_bounds__(256) void lnout_k(
    const float* __restrict__ x, const float* __restrict__ w, const float* __restrict__ b,
    float* __restrict__ xo){
  int tid = threadIdx.x;
  f4 v = ((const f4*)(x + (size_t)(Tn-1)*Dn))[tid];
  f4 st;
  st.x = v.x+v.y+v.z+v.w;
  st.y = v.x*v.x+v.y*v.y+v.z*v.z+v.w*v.w;
  st.z = 0.f; st.w = 0.f;
  f4 red = blockReduce4(st);
  float mu = red.x*(1.f/Dn);
  float rs = rsqrtf(red.y*(1.f/Dn) - mu*mu + 1e-5f);
  f4 wv = ((const f4*)w)[tid], bv = ((const f4*)b)[tid];
  f4 o;
  o.x = (v.x-mu)*rs*wv.x + bv.x;
  o.y = (v.y-mu)*rs*wv.y + bv.y;
  o.z = (v.z-mu)*rs*wv.z + bv.z;
  o.w = (v.w-mu)*rs*wv.w + bv.w;
  ((f4*)xo)[tid] = o;
}

// ------------- head matvec: logits[V] = head[V,D] @ xo[D] -------------
__global__ __launch_bounds__(256) void head_k(
    const float* __restrict__ head, const float* __restrict__ xo, float* __restrict__ out){
  __shared__ f4 sxo[256];
  int tid = threadIdx.x;
  sxo[tid] = ((const f4*)xo)[tid];
  __syncthreads();
  int w = tid >> 6, lane = tid & 63;
  int row = blockIdx.x*4 + w;
  if(row < Vn){
    const f4* hr = (const f4*)(head + (size_t)row*Dn);
    float s = 0.f;
#pragma unroll
    for(int i=0;i<4;i++){
      f4 h = hr[i*64 + lane];
      f4 xv = sxo[i*64 + lane];
      s += h.x*xv.x + h.y*xv.y + h.z*xv.z + h.w*xv.w;
    }
#pragma unroll
    for(int o=32;o;o>>=1) s += __shfl_xor(s, o);
    if(lane == 0) out[row] = s;
  }
}

extern "C" void kernel_launch(void* const* d_in, const int* in_sizes, int n_in,
                              void* d_out, int out_size, void* d_ws, size_t ws_size,
                              hipStream_t stream) {
  (void)in_sizes; (void)n_in; (void)out_size; (void)ws_size;
  const int*   tokens   = (const int*)  d_in[0];
  const float* emb      = (const float*)d_in[1];
  const float* ln0_w    = (const float*)d_in[2];
  const float* ln0_b    = (const float*)d_in[3];
  const float* ln1_w    = (const float*)d_in[4];
  const float* ln1_b    = (const float*)d_in[5];
  const float* ln2_w    = (const float*)d_in[6];
  const float* ln2_b    = (const float*)d_in[7];
  const float* tmk      = (const float*)d_in[8];
  const float* tmv      = (const float*)d_in[9];
  const float* tmr      = (const float*)d_in[10];
  const float* tmk_ffn  = (const float*)d_in[11];
  const float* tmr_ffn  = (const float*)d_in[12];
  const float* tfirst   = (const float*)d_in[13];
  const float* tdecay   = (const float*)d_in[14];
  const float* att_kw   = (const float*)d_in[15];
  const float* att_vw   = (const float*)d_in[16];
  const float* att_rw   = (const float*)d_in[17];
  const float* att_ow   = (const float*)d_in[18];
  const float* ffn_kw   = (const float*)d_in[19];
  const float* ffn_vw   = (const float*)d_in[20];
  const float* ffn_rw   = (const float*)d_in[21];
  const float* lnoutw   = (const float*)d_in[22];
  const float* lnoutb   = (const float*)d_in[23];
  const float* headw    = (const float*)d_in[24];
  float* logits = (float*)d_out;

  char* wsb = (char*)d_ws;
  size_t off = 0;
  auto carve = [&](size_t bytes)->void*{
    void* p = wsb + off;
    off += (bytes + 255) & ~(size_t)255;
    return p;
  };
  float* x      = (float*)carve((size_t)TDn*4);
  u16*   xkvr   = (u16*)  carve((size_t)3*TDn*2);
  float* kvr    = (float*)carve((size_t)3*TDn*4);
  u16*   att_in = (u16*)  carve((size_t)TDn*2);
  u16*   xkr    = (u16*)  carve((size_t)2*TDn*2);
  u16*   kf     = (u16*)  carve((size_t)Tn*F4n*2);
  float* rf     = (float*)carve((size_t)TDn*4);
  float* xo     = (float*)carve((size_t)Dn*4);
  u16*   wbt    = (u16*)  carve((size_t)13*MEG*2);
  float* sega   = (float*)carve((size_t)NSEG*Dn*4);
  float* segb   = (float*)carve((size_t)NSEG*Dn*4);
  float* segp   = (float*)carve((size_t)NSEG*Dn*4);
  float* prea   = (float*)carve((size_t)NSEG*Dn*4);
  float* preb   = (float*)carve((size_t)NSEG*Dn*4);
  float* prep   = (float*)carve((size_t)NSEG*Dn*4);

  embed_ln0_k<<<Tn, 256, 0, stream>>>(tokens, emb, ln0_w, ln0_b, x);

  for(int i=0;i<Ln;i++){
    size_t dd = (size_t)i*Dn*Dn;
    ConvArgs ca;
    ca.s0 = att_kw+dd; ca.s1 = att_vw+dd; ca.s2 = att_rw+dd; ca.s3 = att_ow+dd;
    ca.skw = ffn_kw+(size_t)i*Dn*F4n; ca.svw = ffn_vw+(size_t)i*F4n*Dn; ca.srw = ffn_rw+dd;
    ca.dst = wbt;
    conv_k<<<3328, 256, 0, stream>>>(ca);

    // --- time mix ---
    ln_mix_att_k<<<Tn, 256, 0, stream>>>(x, ln1_w+i*Dn, ln1_b+i*Dn,
                                         tmk+i*Dn, tmv+i*Dn, tmr+i*Dn, xkvr);
    gemm2_k<0><<<dim3(8,8,3), 256, 65536, stream>>>(
        xkvr, Dn, (size_t)TDn, wbt, Dn, (size_t)MEG, Dn, Dn,
        kvr, (size_t)TDn, nullptr);
    wkv_seg_k<<<dim3(4,NSEG), 256, 0, stream>>>(kvr, kvr+TDn, tdecay+i*Dn, sega, segb, segp);
    wkv_scan_k<<<4, 256, 0, stream>>>(sega, segb, segp, tdecay+i*Dn, prea, preb, prep);
    wkv_out_k<<<dim3(4,NSEG), 256, 0, stream>>>(kvr, kvr+TDn, kvr+2*TDn,
                                                tfirst+i*Dn, tdecay+i*Dn,
                                                prea, preb, prep, att_in);
    gemm_k<2,256,4><<<dim3(16,16,1), 256, 131072, stream>>>(
        att_in, Dn, 0, wbt+(size_t)3*MEG, Dn, 0, Dn, Dn,
        x, 0, nullptr, nullptr);
    // --- channel mix ---
    ln_mix_ffn_k<<<Tn, 256, 0, stream>>>(x, ln2_w+i*Dn, ln2_b+i*Dn,
                                         tmk_ffn+i*Dn, tmr_ffn+i*Dn, xkr);
    gemm2_fkr_k<<<dim3(40,8), 256, 65536, stream>>>(
        xkr, wbt+(size_t)4*MEG, wbt+(size_t)12*MEG, kf, rf);
    gemm_k<3,256,4><<<dim3(16,16,1), 256, 131072, stream>>>(
        kf, F4n, 0, wbt+(size_t)8*MEG, F4n, 0, F4n, Dn,
        x, 0, nullptr, rf);
  }

  lnout_k<<<1, 256, 0, stream>>>(x, lnoutw, lnoutb, xo);
  head_k<<<(Vn+3)/4, 256, 0, stream>>>(headw, xo, logits);
}

// Round 15
// 1659.497 us; speedup vs baseline: 1.2441x; 1.0222x over previous
//
#include <hip/hip_runtime.h>

#define Tn 1024
#define Dn 1024
#define Ln 12
#define F4n 4096
#define Vn 50277
#define TDn (Tn*Dn)
#define MEG 1048576
#define SEG 16
#define NSEG 64

typedef __attribute__((ext_vector_type(4))) float f4;
typedef __attribute__((ext_vector_type(16))) float f32x16;
typedef __attribute__((ext_vector_type(8))) short short8;
typedef unsigned short u16;
typedef unsigned int u32;
typedef __attribute__((ext_vector_type(4))) u16 us4;

#define ASG __attribute__((address_space(1)))
#define ASL __attribute__((address_space(3)))

__device__ __forceinline__ u16 f2b(float x){   // f32 -> bf16 RNE
  u32 u = __float_as_uint(x);
  return (u16)((u + 0x7fffu + ((u >> 16) & 1u)) >> 16);
}

// reduce 4 independent sums across a 256-thread block (uses its own LDS)
__device__ __forceinline__ f4 blockReduce4(f4 v){
  __shared__ f4 s[4];
  int lane = threadIdx.x & 63, w = threadIdx.x >> 6;
#pragma unroll
  for(int o = 32; o; o >>= 1){
    v.x += __shfl_xor(v.x, o);
    v.y += __shfl_xor(v.y, o);
    v.z += __shfl_xor(v.z, o);
    v.w += __shfl_xor(v.w, o);
  }
  if(lane == 0) s[w] = v;
  __syncthreads();
  return s[0] + s[1] + s[2] + s[3];
}

// ---------------- merged: per-layer weight convert (blocks 0..3327) + ln_mix_att (3328..4351) ----------------
struct ConvMixArgs {
  // conv part
  const float* s0; const float* s1; const float* s2; const float* s3;  // att k,v,r,o [1024][1024]
  const float* skw;  // [1024][4096]
  const float* svw;  // [4096][1024]
  const float* srw;  // [1024][1024]
  u16* dst;          // 13M elems: k@0 v@1M r@2M o@3M fk@4M fv@8M fr@12M
  // ln_mix_att part
  const float* x;
  const float* lw; const float* lb;
  const float* tk; const float* tv; const float* tr;
  u16* xkvr;
};
__global__ __launch_bounds__(256) void conv_mix_k(ConvMixArgs a){
  __shared__ __align__(16) u16 t[64][68];
  int b = blockIdx.x, tid = threadIdx.x;
  if(b < 3328){
    // ---------------- conv body (byte-identical to R14 conv_k) ----------------
    const float* src; u16* dst; int K, N, tk, tn;
    if(b < 1024){
      int m = b >> 8, bt = b & 255;
      src = (m==0)?a.s0:((m==1)?a.s1:((m==2)?a.s2:a.s3));
      dst = a.dst + (size_t)m*MEG; K=1024; N=1024; tk=bt>>4; tn=bt&15;
    } else if(b < 2048){
      int bt = b-1024; src=a.skw; dst=a.dst+(size_t)4*MEG; K=1024; N=4096; tk=bt>>6; tn=bt&63;
    } else if(b < 3072){
      int bt = b-2048; src=a.svw; dst=a.dst+(size_t)8*MEG; K=4096; N=1024; tk=bt>>4; tn=bt&15;
    } else {
      int bt = b-3072; src=a.srw; dst=a.dst+(size_t)12*MEG; K=1024; N=1024; tk=bt>>4; tn=bt&15;
    }
    int rr0 = tid >> 4, c4 = (tid & 15)*4;
#pragma unroll
    for(int p=0;p<4;p++){
      int r = p*16 + rr0;
      f4 v = *(const f4*)(src + (size_t)(tk*64+r)*N + tn*64 + c4);
      us4 h; h[0]=f2b(v.x); h[1]=f2b(v.y); h[2]=f2b(v.z); h[3]=f2b(v.w);
      *(us4*)&t[r][c4] = h;
    }
    __syncthreads();
    int q = tid & 3, n = tid >> 2;
    int k0 = q*16;
    union { short8 v; u16 h[8]; } o0, o1;
#pragma unroll
    for(int j=0;j<8;j++){ o0.h[j]=t[k0+j][n]; o1.h[j]=t[k0+8+j][n]; }
    u16* dp = dst + (size_t)(tn*64+n)*K + tk*64 + k0;
    *(short8*)dp       = o0.v;
    *(short8*)(dp + 8) = o1.v;
  } else {
    // ---------------- ln_mix_att body (byte-identical to R14 ln_mix_att_k) ----------------
    int tt = b - 3328;
    f4 cur = ((const f4*)(a.x + (size_t)tt*Dn))[tid];
    f4 prv; prv.x=0.f; prv.y=0.f; prv.z=0.f; prv.w=0.f;
    if(tt > 0) prv = ((const f4*)(a.x + (size_t)(tt-1)*Dn))[tid];
    f4 st;
    st.x = cur.x+cur.y+cur.z+cur.w;
    st.y = cur.x*cur.x+cur.y*cur.y+cur.z*cur.z+cur.w*cur.w;
    st.z = prv.x+prv.y+prv.z+prv.w;
    st.w = prv.x*prv.x+prv.y*prv.y+prv.z*prv.z+prv.w*prv.w;
    f4 red = blockReduce4(st);
    float muc = red.x*(1.f/Dn), rsc = rsqrtf(red.y*(1.f/Dn)-muc*muc+1e-5f);
    float mup = red.z*(1.f/Dn), rsp = rsqrtf(red.w*(1.f/Dn)-mup*mup+1e-5f);
    f4 wv=((const f4*)a.lw)[tid], bv=((const f4*)a.lb)[tid];
    f4 kv=((const f4*)a.tk)[tid], vv=((const f4*)a.tv)[tid], rv=((const f4*)a.tr)[tid];
    us4 ok, ov, orr;
    float xn, xp;
#define MIX3(j, cj, pj, wj, bj, kj, vj, rj) \
    xn = (cj - muc)*rsc*wj + bj; \
    xp = (tt>0) ? ((pj - mup)*rsp*wj + bj) : 0.f; \
    ok[j]  = f2b(xn*kj + xp*(1.f-kj)); \
    ov[j]  = f2b(xn*vj + xp*(1.f-vj)); \
    orr[j] = f2b(xn*rj + xp*(1.f-rj));
    MIX3(0, cur.x, prv.x, wv.x, bv.x, kv.x, vv.x, rv.x)
    MIX3(1, cur.y, prv.y, wv.y, bv.y, kv.y, vv.y, rv.y)
    MIX3(2, cur.z, prv.z, wv.z, bv.z, kv.z, vv.z, rv.z)
    MIX3(3, cur.w, prv.w, wv.w, bv.w, kv.w, vv.w, rv.w)
#undef MIX3
    size_t o0 = (size_t)tt*Dn + tid*4;
    *(us4*)(a.xkvr + o0)         = ok;
    *(us4*)(a.xkvr + TDn + o0)   = ov;
    *(us4*)(a.xkvr + 2*TDn + o0) = orr;
  }
}

// ---------------- embedding + ln0 ----------------
__global__ __launch_bounds__(256) void embed_ln0_k(
    const int* __restrict__ tok, const float* __restrict__ emb,
    const float* __restrict__ w, const float* __restrict__ b,
    float* __restrict__ x){
  int t = blockIdx.x, tid = threadIdx.x;
  const f4* src = (const f4*)(emb + (size_t)tok[t] * Dn);
  f4 v = src[tid];
  f4 st;
  st.x = v.x+v.y+v.z+v.w;
  st.y = v.x*v.x+v.y*v.y+v.z*v.z+v.w*v.w;
  st.z = 0.f; st.w = 0.f;
  f4 red = blockReduce4(st);
  float mu = red.x * (1.0f/Dn);
  float rs = rsqrtf(red.y * (1.0f/Dn) - mu*mu + 1e-5f);
  f4 wv = ((const f4*)w)[tid], bv = ((const f4*)b)[tid];
  f4 o;
  o.x = (v.x-mu)*rs*wv.x + bv.x;
  o.y = (v.y-mu)*rs*wv.y + bv.y;
  o.z = (v.z-mu)*rs*wv.z + bv.z;
  o.w = (v.w-mu)*rs*wv.w + bv.w;
  ((f4*)(x + (size_t)t*Dn))[tid] = o;
}

// ------------- LN + token-shift + mix (ffn: k,r) -------------
__global__ __launch_bounds__(256) void ln_mix_ffn_k(
    const float* __restrict__ x,
    const float* __restrict__ lw, const float* __restrict__ lb,
    const float* __restrict__ tk, const float* __restrict__ tr,
    u16* __restrict__ xkr){
  int t = blockIdx.x, tid = threadIdx.x;
  f4 cur = ((const f4*)(x + (size_t)t*Dn))[tid];
  f4 prv; prv.x=0.f; prv.y=0.f; prv.z=0.f; prv.w=0.f;
  if(t > 0) prv = ((const f4*)(x + (size_t)(t-1)*Dn))[tid];
  f4 st;
  st.x = cur.x+cur.y+cur.z+cur.w;
  st.y = cur.x*cur.x+cur.y*cur.y+cur.z*cur.z+cur.w*cur.w;
  st.z = prv.x+prv.y+prv.z+prv.w;
  st.w = prv.x*prv.x+prv.y*prv.y+prv.z*prv.z+prv.w*prv.w;
  f4 red = blockReduce4(st);
  float muc = red.x*(1.f/Dn), rsc = rsqrtf(red.y*(1.f/Dn)-muc*muc+1e-5f);
  float mup = red.z*(1.f/Dn), rsp = rsqrtf(red.w*(1.f/Dn)-mup*mup+1e-5f);
  f4 wv=((const f4*)lw)[tid], bv=((const f4*)lb)[tid];
  f4 kv=((const f4*)tk)[tid], rv=((const f4*)tr)[tid];
  us4 ok, orr;
  float xn, xp;
#define MIX2(j, cj, pj, wj, bj, kj, rj) \
  xn = (cj - muc)*rsc*wj + bj; \
  xp = (t>0) ? ((pj - mup)*rsp*wj + bj) : 0.f; \
  ok[j]  = f2b(xn*kj + xp*(1.f-kj)); \
  orr[j] = f2b(xn*rj + xp*(1.f-rj));
  MIX2(0, cur.x, prv.x, wv.x, bv.x, kv.x, rv.x)
  MIX2(1, cur.y, prv.y, wv.y, bv.y, kv.y, rv.y)
  MIX2(2, cur.z, prv.z, wv.z, bv.z, kv.z, rv.z)
  MIX2(3, cur.w, prv.w, wv.w, bv.w, kv.w, rv.w)
#undef MIX2
  size_t o0 = (size_t)t*Dn + tid*4;
  *(us4*)(xkr + o0)       = ok;
  *(us4*)(xkr + TDn + o0) = orr;
}

// ------------- WKV chunked scan, pass 1 -------------
__global__ __launch_bounds__(256) void wkv_seg_k(
    const float* __restrict__ kb, const float* __restrict__ vb,
    const float* __restrict__ tdp,
    float* __restrict__ sega, float* __restrict__ segb, float* __restrict__ segp){
  int ch = blockIdx.x*256 + threadIdx.x;
  int g = blockIdx.y;
  int t0 = g*SEG;
  float td = tdp[ch];
  float kk[SEG], vv[SEG];
#pragma unroll
  for(int j=0;j<SEG;j++){
    kk[j] = kb[(size_t)(t0+j)*Dn + ch];
    vv[j] = vb[(size_t)(t0+j)*Dn + ch];
  }
  float aa=0.f, bb=0.f, pp=-1e30f;
#pragma unroll
  for(int j=0;j<SEG;j++){
    float ww2 = pp + td;
    float p2 = fmaxf(ww2, kk[j]);
    float e1 = __expf(ww2-p2), e2 = __expf(kk[j]-p2);
    aa = e1*aa + e2*vv[j]; bb = e1*bb + e2; pp = p2;
  }
  size_t o = (size_t)g*Dn + ch;
  sega[o] = aa; segb[o] = bb; segp[o] = pp;
}

// ------------- WKV pass 2: serial compose over segments -------------
__global__ __launch_bounds__(256) void wkv_scan_k(
    const float* __restrict__ sega, const float* __restrict__ segb, const float* __restrict__ segp,
    const float* __restrict__ tdp,
    float* __restrict__ prea, float* __restrict__ preb, float* __restrict__ prep){
  int ch = blockIdx.x*256 + threadIdx.x;
  float Std = tdp[ch] * (float)SEG;
  float a=0.f, b=0.f, p=-1e30f;
  for(int g=0; g<NSEG; g++){
    size_t o = (size_t)g*Dn + ch;
    prea[o]=a; preb[o]=b; prep[o]=p;
    float ag=sega[o], bg=segb[o], qg=segp[o];
    float psh = p + Std;
    float pn = fmaxf(psh, qg);
    float eo = __expf(psh-pn), en = __expf(qg-pn);
    a = eo*a + en*ag; b = eo*b + en*bg; p = pn;
  }
}

// ------------- WKV pass 3: expand from incoming state, fuse sigmoid(r) -------------
__global__ __launch_bounds__(256) void wkv_out_k(
    const float* __restrict__ kb, const float* __restrict__ vb, const float* __restrict__ rb,
    const float* __restrict__ tfp, const float* __restrict__ tdp,
    const float* __restrict__ prea, const float* __restrict__ preb, const float* __restrict__ prep,
    u16* __restrict__ att_in){
  int ch = blockIdx.x*256 + threadIdx.x;
  int g = blockIdx.y;
  int t0 = g*SEG;
  float tf = tfp[ch], td = tdp[ch];
  size_t so = (size_t)g*Dn + ch;
  float aa = prea[so], bb = preb[so], pp = prep[so];
  float kk[SEG], vv[SEG], rr[SEG];
#pragma unroll
  for(int j=0;j<SEG;j++){
    kk[j]=kb[(size_t)(t0+j)*Dn+ch];
    vv[j]=vb[(size_t)(t0+j)*Dn+ch];
    rr[j]=rb[(size_t)(t0+j)*Dn+ch];
  }
#pragma unroll
  for(int j=0;j<SEG;j++){
    float kt=kk[j], vt=vv[j];
    float ww = tf + kt;
    float p = fmaxf(pp, ww);
    float e1 = __expf(pp-p), e2 = __expf(ww-p);
    float out = __fdividef(e1*aa+e2*vt, e1*bb+e2);
    float sig = __fdividef(1.f, 1.f+__expf(-rr[j]));
    att_in[(size_t)(t0+j)*Dn+ch] = f2b(sig*out);
    float ww2 = pp+td;
    float p2 = fmaxf(ww2,kt);
    e1 = __expf(ww2-p2); e2 = __expf(kt-p2);
    aa = e1*aa+e2*vt; bb = e1*bb+e2; pp = p2;
  }
}

// ------------- bf16 GEMM (R10-proven): 64x64 tile, WAVES-way split-K, dyn LDS -------------
// EPI 0: Cf(+z*strideC) = acc   EPI 2: Cf += acc   EPI 3: Cf += sigmoid(aux)*acc
template<int EPI, int KSTEP, int WAVES>
__global__ __launch_bounds__(WAVES*64) void gemm_k(
    const u16* __restrict__ A, size_t ldA, size_t strideA,
    const u16* __restrict__ Bt, size_t ldB, size_t strideB,
    int K, int N,
    float* __restrict__ Cf, size_t strideC, u16* __restrict__ Cb,
    const float* __restrict__ aux){
  extern __shared__ __align__(16) u16 ldsd[];     // [2 buf][2 op][64*KSTEP]
  constexpr int RPC = 512/KSTEP;
  constexpr int LPR = 64/RPC;
  constexpr int NCH = KSTEP/8;
  constexpr int NQ  = NCH/WAVES;
  constexpr int WKB = 2*KSTEP/WAVES;
  constexpr int NS  = WKB/32;
  const int tid = threadIdx.x;
  const int l = tid & 63, w = tid >> 6;
  const int z = blockIdx.z;
  const int row0 = blockIdx.y*64, col0 = blockIdx.x*64;

  const u16* bA = A  + (size_t)z*strideA + (size_t)row0*ldA;
  const u16* bB = Bt + (size_t)z*strideB + (size_t)col0*ldB;

  int offA[NQ], offB[NQ], ldso[NQ];
#pragma unroll
  for(int q=0;q<NQ;q++){
    int ch = q*WAVES + w;
    int r  = ch*RPC + l/LPR;
    int phys = (l%LPR)*16;
    int kk = ((phys ^ ((r&15)<<4)) >> 1);
    offA[q] = r*(int)ldA + kk;
    offB[q] = r*(int)ldB + kk;
    ldso[q] = ch*512;
  }
  int foff[2][NS];
#pragma unroll
  for(int i=0;i<2;i++){
    int row = i*32 + (l&31);
#pragma unroll
    for(int s=0;s<NS;s++){
      int c = w*WKB + s*32 + ((l>>5)*16);
      foff[i][s] = row*KSTEP + ((c ^ ((row&15)<<4)) >> 1);
    }
  }

  f32x16 acc[2][2];
#pragma unroll
  for(int i=0;i<2;i++)
#pragma unroll
    for(int j=0;j<2;j++)
#pragma unroll
      for(int e=0;e<16;e++) acc[i][j][e] = 0.f;

  u16* ldsA0 = ldsd;
  u16* ldsB0 = ldsd + 64*KSTEP;
  u16* ldsA1 = ldsd + 2*64*KSTEP;
  u16* ldsB1 = ldsd + 3*64*KSTEP;

#define STAGE(LA, LB) do{ \
  _Pragma("unroll") \
  for(int q=0;q<NQ;q++){ \
    __builtin_amdgcn_global_load_lds((ASG const void*)(const void*)(bA + offA[q]), (ASL void*)(void*)((LA) + ldso[q]), 16, 0, 0); \
    __builtin_amdgcn_global_load_lds((ASG const void*)(const void*)(bB + offB[q]), (ASL void*)(void*)((LB) + ldso[q]), 16, 0, 0); \
  } \
  bA += KSTEP; bB += KSTEP; }while(0)

  const int nss = K / KSTEP;
  STAGE(ldsA0, ldsB0);
  __syncthreads();
  int buf = 0;
  for(int ss=0; ss<nss; ss++){
    if(ss+1 < nss){
      if(buf) STAGE(ldsA0, ldsB0); else STAGE(ldsA1, ldsB1);
    }
    const u16* La = buf ? ldsA1 : ldsA0;
    const u16* Lb = buf ? ldsB1 : ldsB0;
#pragma unroll
    for(int s=0;s<NS;s++){
      short8 a0 = *(const short8*)(La + foff[0][s]);
      short8 a1 = *(const short8*)(La + foff[1][s]);
      short8 b0 = *(const short8*)(Lb + foff[0][s]);
      short8 b1 = *(const short8*)(Lb + foff[1][s]);
      acc[0][0] = __builtin_amdgcn_mfma_f32_32x32x16_bf16(a0, b0, acc[0][0], 0, 0, 0);
      acc[0][1] = __builtin_amdgcn_mfma_f32_32x32x16_bf16(a0, b1, acc[0][1], 0, 0, 0);
      acc[1][0] = __builtin_amdgcn_mfma_f32_32x32x16_bf16(a1, b0, acc[1][0], 0, 0, 0);
      acc[1][1] = __builtin_amdgcn_mfma_f32_32x32x16_bf16(a1, b1, acc[1][1], 0, 0, 0);
    }
    __syncthreads();
    buf ^= 1;
  }
#undef STAGE

  float* red = (float*)ldsd;
  if(w > 0){
#pragma unroll
    for(int i=0;i<2;i++)
#pragma unroll
      for(int j=0;j<2;j++)
#pragma unroll
        for(int reg=0;reg<16;reg++){
          int rr_ = (reg&3) + 8*(reg>>2) + 4*(l>>5);
          red[(size_t)(w-1)*4096 + (size_t)(i*32 + rr_)*64 + j*32 + (l&31)] = acc[i][j][reg];
        }
  }
  __syncthreads();
  if(w == 0){
#pragma unroll
    for(int i=0;i<2;i++)
#pragma unroll
      for(int j=0;j<2;j++)
#pragma unroll
        for(int reg=0;reg<16;reg++){
          int rr_ = (reg&3) + 8*(reg>>2) + 4*(l>>5);
          size_t lidx = (size_t)(i*32 + rr_)*64 + j*32 + (l&31);
          float v = acc[i][j][reg];
#pragma unroll
          for(int p=0;p<WAVES-1;p++) v += red[(size_t)p*4096 + lidx];
          int grow = row0 + i*32 + rr_;
          int gcol = col0 + j*32 + (l&31);
          size_t idx = (size_t)grow*N + gcol;
          if constexpr(EPI==0){ Cf[(size_t)z*strideC + idx] = v; }
          else if constexpr(EPI==2){ Cf[idx] += v; }
          else { float s_ = __fdividef(1.f, 1.f+__expf(-aux[idx])); Cf[idx] += s_*v; }
        }
  }
}

// ------------- 128x128-tile GEMM (R12/R13-proven): KSTEP=64, 4 waves in 2x2 quadrants -------------
// EPI 0: Cf[z*strideC + idx] = acc (fp32)   EPI 1: Cb = bf16(relu(acc)^2)
template<int EPI>
__global__ __launch_bounds__(256) void gemm2_k(
    const u16* __restrict__ A, size_t ldA, size_t strideA,
    const u16* __restrict__ Bt, size_t ldB, size_t strideB,
    int K, int N,
    float* __restrict__ Cf, size_t strideC, u16* __restrict__ Cb){
  extern __shared__ __align__(16) u16 ldsd[];
  constexpr int KS = 64;
  const int tid = threadIdx.x;
  const int l = tid & 63, w = tid >> 6;
  const int wm = (w>>1)*64, wn = (w&1)*64;
  const int z = blockIdx.z;
  const int row0 = blockIdx.y*128, col0 = blockIdx.x*128;

  const u16* bA = A  + (size_t)z*strideA + (size_t)row0*ldA;
  const u16* bB = Bt + (size_t)z*strideB + (size_t)col0*ldB;

  int offA[4], offB[4], ldso[4];
#pragma unroll
  for(int q=0;q<4;q++){
    int ch = q*4 + w;
    int r  = ch*8 + (l>>3);
    int kk = ((((l&7)*16) ^ ((l>>3)<<4)) >> 1);
    offA[q] = r*(int)ldA + kk;
    offB[q] = r*(int)ldB + kk;
    ldso[q] = ch*512;
  }
  int foffA[2][4], foffB[2][4];
#pragma unroll
  for(int i=0;i<2;i++){
    int ar = wm + i*32 + (l&31);
    int br = wn + i*32 + (l&31);
#pragma unroll
    for(int s=0;s<4;s++){
      int c = s*32 + ((l>>5)*16);
      foffA[i][s] = ar*KS + ((c ^ ((ar&7)<<4)) >> 1);
      foffB[i][s] = br*KS + ((c ^ ((br&7)<<4)) >> 1);
    }
  }

  f32x16 acc[2][2];
#pragma unroll
  for(int i=0;i<2;i++)
#pragma unroll
    for(int j=0;j<2;j++)
#pragma unroll
      for(int e=0;e<16;e++) acc[i][j][e] = 0.f;

  u16* ldsA0 = ldsd;
  u16* ldsB0 = ldsd + 8192;
  u16* ldsA1 = ldsd + 16384;
  u16* ldsB1 = ldsd + 24576;

#define STAGE(LA, LB) do{ \
  _Pragma("unroll") \
  for(int q=0;q<4;q++){ \
    __builtin_amdgcn_global_load_lds((ASG const void*)(const void*)(bA + offA[q]), (ASL void*)(void*)((LA) + ldso[q]), 16, 0, 0); \
    __builtin_amdgcn_global_load_lds((ASG const void*)(const void*)(bB + offB[q]), (ASL void*)(void*)((LB) + ldso[q]), 16, 0, 0); \
  } \
  bA += KS; bB += KS; }while(0)

  const int nss = K / KS;
  STAGE(ldsA0, ldsB0);
  __syncthreads();
  int buf = 0;
#pragma unroll 1
  for(int ss=0; ss<nss; ss++){
    if(ss+1 < nss){
      if(buf) STAGE(ldsA0, ldsB0); else STAGE(ldsA1, ldsB1);
    }
    const u16* La = buf ? ldsA1 : ldsA0;
    const u16* Lb = buf ? ldsB1 : ldsB0;
#pragma unroll
    for(int s=0;s<4;s++){
      short8 a0 = *(const short8*)(La + foffA[0][s]);
      short8 a1 = *(const short8*)(La + foffA[1][s]);
      short8 b0 = *(const short8*)(Lb + foffB[0][s]);
      short8 b1 = *(const short8*)(Lb + foffB[1][s]);
      acc[0][0] = __builtin_amdgcn_mfma_f32_32x32x16_bf16(a0, b0, acc[0][0], 0, 0, 0);
      acc[0][1] = __builtin_amdgcn_mfma_f32_32x32x16_bf16(a0, b1, acc[0][1], 0, 0, 0);
      acc[1][0] = __builtin_amdgcn_mfma_f32_32x32x16_bf16(a1, b0, acc[1][0], 0, 0, 0);
      acc[1][1] = __builtin_amdgcn_mfma_f32_32x32x16_bf16(a1, b1, acc[1][1], 0, 0, 0);
    }
    __syncthreads();
    buf ^= 1;
  }
#undef STAGE

#pragma unroll
  for(int i=0;i<2;i++){
#pragma unroll
    for(int j=0;j<2;j++){
#pragma unroll
      for(int reg=0;reg<16;reg++){
        int rr_ = (reg&3) + 8*(reg>>2) + 4*(l>>5);
        int grow = row0 + wm + i*32 + rr_;
        int gcol = col0 + wn + j*32 + (l&31);
        float v = acc[i][j][reg];
        size_t idx = (size_t)grow*N + gcol;
        if constexpr(EPI==0){ Cf[(size_t)z*strideC + idx] = v; }
        else { float t_ = v>0.f ? v : 0.f; Cb[idx] = f2b(t_*t_); }
      }
    }
  }
}

// ------------- merged FFN-k + FFN-r at 128x128 geometry (R14-proven): grid (40,8) -------------
__global__ __launch_bounds__(256) void gemm2_fkr_k(
    const u16* __restrict__ xkr, const u16* __restrict__ wfk, const u16* __restrict__ wfr,
    u16* __restrict__ kf, float* __restrict__ rf){
  extern __shared__ __align__(16) u16 ldsd[];
  constexpr int KS = 64;
  const int tid = threadIdx.x;
  const int l = tid & 63, w = tid >> 6;
  const int wm = (w>>1)*64, wn = (w&1)*64;
  const bool isfk = blockIdx.x < 32;
  const int N = isfk ? F4n : Dn;
  const int col0 = (isfk ? blockIdx.x : blockIdx.x-32)*128;
  const int row0 = blockIdx.y*128;

  const u16* bA = (isfk ? xkr : xkr + TDn) + (size_t)row0*Dn;
  const u16* bB = (isfk ? wfk : wfr) + (size_t)col0*Dn;

  int offA[4], offB[4], ldso[4];
#pragma unroll
  for(int q=0;q<4;q++){
    int ch = q*4 + w;
    int r  = ch*8 + (l>>3);
    int kk = ((((l&7)*16) ^ ((l>>3)<<4)) >> 1);
    offA[q] = r*Dn + kk;
    offB[q] = r*Dn + kk;
    ldso[q] = ch*512;
  }
  int foffA[2][4], foffB[2][4];
#pragma unroll
  for(int i=0;i<2;i++){
    int ar = wm + i*32 + (l&31);
    int br = wn + i*32 + (l&31);
#pragma unroll
    for(int s=0;s<4;s++){
      int c = s*32 + ((l>>5)*16);
      foffA[i][s] = ar*KS + ((c ^ ((ar&7)<<4)) >> 1);
      foffB[i][s] = br*KS + ((c ^ ((br&7)<<4)) >> 1);
    }
  }

  f32x16 acc[2][2];
#pragma unroll
  for(int i=0;i<2;i++)
#pragma unroll
    for(int j=0;j<2;j++)
#pragma unroll
      for(int e=0;e<16;e++) acc[i][j][e] = 0.f;

  u16* ldsA0 = ldsd;
  u16* ldsB0 = ldsd + 8192;
  u16* ldsA1 = ldsd + 16384;
  u16* ldsB1 = ldsd + 24576;

#define STAGE(LA, LB) do{ \
  _Pragma("unroll") \
  for(int q=0;q<4;q++){ \
    __builtin_amdgcn_global_load_lds((ASG const void*)(const void*)(bA + offA[q]), (ASL void*)(void*)((LA) + ldso[q]), 16, 0, 0); \
    __builtin_amdgcn_global_load_lds((ASG const void*)(const void*)(bB + offB[q]), (ASL void*)(void*)((LB) + ldso[q]), 16, 0, 0); \
  } \
  bA += KS; bB += KS; }while(0)

  STAGE(ldsA0, ldsB0);
  __syncthreads();
  int buf = 0;
#pragma unroll 1
  for(int ss=0; ss<16; ss++){
    if(ss+1 < 16){
      if(buf) STAGE(ldsA0, ldsB0); else STAGE(ldsA1, ldsB1);
    }
    const u16* La = buf ? ldsA1 : ldsA0;
    const u16* Lb = buf ? ldsB1 : ldsB0;
#pragma unroll
    for(int s=0;s<4;s++){
      short8 a0 = *(const short8*)(La + foffA[0][s]);
      short8 a1 = *(const short8*)(La + foffA[1][s]);
      short8 b0 = *(const short8*)(Lb + foffB[0][s]);
      short8 b1 = *(const short8*)(Lb + foffB[1][s]);
      acc[0][0] = __builtin_amdgcn_mfma_f32_32x32x16_bf16(a0, b0, acc[0][0], 0, 0, 0);
      acc[0][1] = __builtin_amdgcn_mfma_f32_32x32x16_bf16(a0, b1, acc[0][1], 0, 0, 0);
      acc[1][0] = __builtin_amdgcn_mfma_f32_32x32x16_bf16(a1, b0, acc[1][0], 0, 0, 0);
      acc[1][1] = __builtin_amdgcn_mfma_f32_32x32x16_bf16(a1, b1, acc[1][1], 0, 0, 0);
    }
    __syncthreads();
    buf ^= 1;
  }
#undef STAGE

#pragma unroll
  for(int i=0;i<2;i++){
#pragma unroll
    for(int j=0;j<2;j++){
#pragma unroll
      for(int reg=0;reg<16;reg++){
        int rr_ = (reg&3) + 8*(reg>>2) + 4*(l>>5);
        int grow = row0 + wm + i*32 + rr_;
        int gcol = col0 + wn + j*32 + (l&31);
        float v = acc[i][j][reg];
        size_t idx = (size_t)grow*N + gcol;
        if(isfk){ float t_ = v>0.f ? v : 0.f; kf[idx] = f2b(t_*t_); }
        else rf[idx] = v;
      }
    }
  }
}

// ------------- final LN of last row -------------
__global__ __launch_bounds__(256) void lnout_k(
    const float* __restrict__ x, const float* __restrict__ w, const float* __restrict__ b,
    float* __restrict__ xo){
  int tid = threadIdx.x;
  f4 v = ((const f4*)(x + (size_t)(Tn-1)*Dn))[tid];
  f4 st;
  st.x = v.x+v.y+v.z+v.w;
  st.y = v.x*v.x+v.y*v.y+v.z*v.z+v.w*v.w;
  st.z = 0.f; st.w = 0.f;
  f4 red = blockReduce4(st);
  float mu = red.x*(1.f/Dn);
  float rs = rsqrtf(red.y*(1.f/Dn) - mu*mu + 1e-5f);
  f4 wv = ((const f4*)w)[tid], bv = ((const f4*)b)[tid];
  f4 o;
  o.x = (v.x-mu)*rs*wv.x + bv.x;
  o.y = (v.y-mu)*rs*wv.y + bv.y;
  o.z = (v.z-mu)*rs*wv.z + bv.z;
  o.w = (v.w-mu)*rs*wv.w + bv.w;
  ((f4*)xo)[tid] = o;
}

// ------------- head matvec: logits[V] = head[V,D] @ xo[D] -------------
__global__ __launch_bounds__(256) void head_k(
    const float* __restrict__ head, const float* __restrict__ xo, float* __restrict__ out){
  __shared__ f4 sxo[256];
  int tid = threadIdx.x;
  sxo[tid] = ((const f4*)xo)[tid];
  __syncthreads();
  int w = tid >> 6, lane = tid & 63;
  int row = blockIdx.x*4 + w;
  if(row < Vn){
    const f4* hr = (const f4*)(head + (size_t)row*Dn);
    float s = 0.f;
#pragma unroll
    for(int i=0;i<4;i++){
      f4 h = hr[i*64 + lane];
      f4 xv = sxo[i*64 + lane];
      s += h.x*xv.x + h.y*xv.y + h.z*xv.z + h.w*xv.w;
    }
#pragma unroll
    for(int o=32;o;o>>=1) s += __shfl_xor(s, o);
    if(lane == 0) out[row] = s;
  }
}

extern "C" void kernel_launch(void* const* d_in, const int* in_sizes, int n_in,
                              void* d_out, int out_size, void* d_ws, size_t ws_size,
                              hipStream_t stream) {
  (void)in_sizes; (void)n_in; (void)out_size; (void)ws_size;
  const int*   tokens   = (const int*)  d_in[0];
  const float* emb      = (const float*)d_in[1];
  const float* ln0_w    = (const float*)d_in[2];
  const float* ln0_b    = (const float*)d_in[3];
  const float* ln1_w    = (const float*)d_in[4];
  const float* ln1_b    = (const float*)d_in[5];
  const float* ln2_w    = (const float*)d_in[6];
  const float* ln2_b    = (const float*)d_in[7];
  const float* tmk      = (const float*)d_in[8];
  const float* tmv      = (const float*)d_in[9];
  const float* tmr      = (const float*)d_in[10];
  const float* tmk_ffn  = (const float*)d_in[11];
  const float* tmr_ffn  = (const float*)d_in[12];
  const float* tfirst   = (const float*)d_in[13];
  const float* tdecay   = (const float*)d_in[14];
  const float* att_kw   = (const float*)d_in[15];
  const float* att_vw   = (const float*)d_in[16];
  const float* att_rw   = (const float*)d_in[17];
  const float* att_ow   = (const float*)d_in[18];
  const float* ffn_kw   = (const float*)d_in[19];
  const float* ffn_vw   = (const float*)d_in[20];
  const float* ffn_rw   = (const float*)d_in[21];
  const float* lnoutw   = (const float*)d_in[22];
  const float* lnoutb   = (const float*)d_in[23];
  const float* headw    = (const float*)d_in[24];
  float* logits = (float*)d_out;

  char* wsb = (char*)d_ws;
  size_t off = 0;
  auto carve = [&](size_t bytes)->void*{
    void* p = wsb + off;
    off += (bytes + 255) & ~(size_t)255;
    return p;
  };
  float* x      = (float*)carve((size_t)TDn*4);
  u16*   xkvr   = (u16*)  carve((size_t)3*TDn*2);
  float* kvr    = (float*)carve((size_t)3*TDn*4);
  u16*   att_in = (u16*)  carve((size_t)TDn*2);
  u16*   xkr    = (u16*)  carve((size_t)2*TDn*2);
  u16*   kf     = (u16*)  carve((size_t)Tn*F4n*2);
  float* rf     = (float*)carve((size_t)TDn*4);
  float* xo     = (float*)carve((size_t)Dn*4);
  u16*   wbt    = (u16*)  carve((size_t)13*MEG*2);
  float* sega   = (float*)carve((size_t)NSEG*Dn*4);
  float* segb   = (float*)carve((size_t)NSEG*Dn*4);
  float* segp   = (float*)carve((size_t)NSEG*Dn*4);
  float* prea   = (float*)carve((size_t)NSEG*Dn*4);
  float* preb   = (float*)carve((size_t)NSEG*Dn*4);
  float* prep   = (float*)carve((size_t)NSEG*Dn*4);

  embed_ln0_k<<<Tn, 256, 0, stream>>>(tokens, emb, ln0_w, ln0_b, x);

  for(int i=0;i<Ln;i++){
    size_t dd = (size_t)i*Dn*Dn;
    ConvMixArgs ca;
    ca.s0 = att_kw+dd; ca.s1 = att_vw+dd; ca.s2 = att_rw+dd; ca.s3 = att_ow+dd;
    ca.skw = ffn_kw+(size_t)i*Dn*F4n; ca.svw = ffn_vw+(size_t)i*F4n*Dn; ca.srw = ffn_rw+dd;
    ca.dst = wbt;
    ca.x = x; ca.lw = ln1_w+i*Dn; ca.lb = ln1_b+i*Dn;
    ca.tk = tmk+i*Dn; ca.tv = tmv+i*Dn; ca.tr = tmr+i*Dn;
    ca.xkvr = xkvr;
    // merged conv (blocks 0..3327) + ln_mix_att (3328..4351)
    conv_mix_k<<<4352, 256, 0, stream>>>(ca);

    // --- time mix ---
    gemm2_k<0><<<dim3(8,8,3), 256, 65536, stream>>>(
        xkvr, Dn, (size_t)TDn, wbt, Dn, (size_t)MEG, Dn, Dn,
        kvr, (size_t)TDn, nullptr);
    wkv_seg_k<<<dim3(4,NSEG), 256, 0, stream>>>(kvr, kvr+TDn, tdecay+i*Dn, sega, segb, segp);
    wkv_scan_k<<<4, 256, 0, stream>>>(sega, segb, segp, tdecay+i*Dn, prea, preb, prep);
    wkv_out_k<<<dim3(4,NSEG), 256, 0, stream>>>(kvr, kvr+TDn, kvr+2*TDn,
                                                tfirst+i*Dn, tdecay+i*Dn,
                                                prea, preb, prep, att_in);
    gemm_k<2,256,4><<<dim3(16,16,1), 256, 131072, stream>>>(
        att_in, Dn, 0, wbt+(size_t)3*MEG, Dn, 0, Dn, Dn,
        x, 0, nullptr, nullptr);
    // --- channel mix ---
    ln_mix_ffn_k<<<Tn, 256, 0, stream>>>(x, ln2_w+i*Dn, ln2_b+i*Dn,
                                         tmk_ffn+i*Dn, tmr_ffn+i*Dn, xkr);
    gemm2_fkr_k<<<dim3(40,8), 256, 65536, stream>>>(
        xkr, wbt+(size_t)4*MEG, wbt+(size_t)12*MEG, kf, rf);
    gemm_k<3,256,4><<<dim3(16,16,1), 256, 131072, stream>>>(
        kf, F4n, 0, wbt+(size_t)8*MEG, F4n, 0, F4n, Dn,
        x, 0, nullptr, rf);
  }

  lnout_k<<<1, 256, 0, stream>>>(x, lnoutw, lnoutb, xo);
  head_k<<<(Vn+3)/4, 256, 0, stream>>>(headw, xo, logits);
}